// Round 9
// baseline (779.039 us; speedup 1.0000x reference)
//
#include <hip/hip_runtime.h>
#include <hip/hip_bf16.h>
#include <cstdint>
#include <cstddef>

#define Sd 1024
#define Dd 512
#define Hd 8
#define Fd 2048
#define Bd 8
#define EPSf 1e-3f

typedef __bf16 bf16x8 __attribute__((ext_vector_type(8)));
typedef float f32x4 __attribute__((ext_vector_type(4)));
typedef __attribute__((address_space(3))) unsigned int lds_u32;
typedef __attribute__((address_space(1))) const unsigned int gl_u32;

#define BM 128
#define BN 128
#define BK 32

enum { EPI_BF16 = 0, EPI_F32 = 1, EPI_BNPRELU = 2, EPI_SCORES = 3, EPI_PV = 4 };

__device__ __forceinline__ void gl_lds16(const void* g, void* l) {
  __builtin_amdgcn_global_load_lds((gl_u32*)g, (lds_u32*)l, 16, 0, 0);
}

// ======================================================================
// 256x256 GEMM v4: A via 3-deep LDS ring (96KiB, staged 2 tiles ahead,
// counted vmcnt, never 0 mid-loop), B direct global->VGPR (asm loads,
// reg-reuse after last consumer). LDS reads/tile: 192KB -> 128KB.
// C[M,N] = epi(A @ Bt^T + bias), A [M,K] bf16, Bt [N,K] bf16.
// M%256==0, N%256==0, K%64==0, NT>=3, grid (N/256, M/256), nwg%8==0.
// vmcnt queue/tile u (steady): [A(u+2)@p1][bA(u+1)@p2][bB(u+1)@p4]
//   p1: VMC(8) retires bA(u) [and A(u+1), issued earlier]
//   p3: VMC(8) retires bB(u)
//   tail (u+2>=NT): VMC(0) both (conservative, last 2 tiles only).
// lgkm/tile: p1 issues 8 ds (aA,aB), LGKM(4)->aA; p2 +4, LGKM(4)->aB;
//   p3 +4, LGKM(4)->aA'; p4 LGKM(0)->aB'. One s_barrier per tile (WAR:
//   ring slot's readers finished >=1 barrier before its restage issues).
// ======================================================================

#define LGKM(n)                                                  \
  asm volatile("s_waitcnt lgkmcnt(" #n ")" ::: "memory");        \
  __builtin_amdgcn_sched_barrier(0)
#define VMC(n)                                                   \
  asm volatile("s_waitcnt vmcnt(" #n ")" ::: "memory");          \
  __builtin_amdgcn_sched_barrier(0)

#define LDA_(dst, qoff, xr, mh)                                              \
  _Pragma("unroll") for (int i_ = 0; i_ < 4; ++i_)                           \
      dst[i_] = *(const bf16x8*)(aw + (qoff) + (xr) + (mh) * 8192 + i_ * 2048);
#define LOADB4(set, OFFS)                                                    \
  _Pragma("unroll") for (int i_ = 0; i_ < 4; ++i_)                           \
      asm volatile("global_load_dwordx4 %0, %1, off offset:" OFFS            \
                   : "=v"(set[i_]) : "v"(bptr[i_]) : "memory");
#define MFMAQ(q, av, bv)                                                     \
  __builtin_amdgcn_s_setprio(1);                                             \
  {                                                                          \
    _Pragma("unroll") for (int i_ = 0; i_ < 4; ++i_) {                       \
      _Pragma("unroll") for (int n_ = 0; n_ < 4; ++n_)                       \
          acc[(q) * 4 + i_][n_] = __builtin_amdgcn_mfma_f32_16x16x32_bf16(   \
              av[i_], bv[n_], acc[(q) * 4 + i_], 0, 0, 0)[n_] , acc[(q)*4+i_][n_]; \
    }                                                                        \
  }                                                                          \
  __builtin_amdgcn_s_setprio(0)
// NOTE: the MFMAQ above is wrong-looking; real one defined below.
#undef MFMAQ
#define MFMAQ(q, av, bv)                                                     \
  __builtin_amdgcn_s_setprio(1);                                             \
  {                                                                          \
    _Pragma("unroll") for (int i_ = 0; i_ < 4; ++i_) {                       \
      _Pragma("unroll") for (int n_ = 0; n_ < 4; ++n_)                       \
          acc[(q) * 4 + i_][n_] = __builtin_amdgcn_mfma_f32_16x16x32_bf16(   \
              av[i_], bv[n_], acc[(q) * 4 + i_][n_], 0, 0, 0);               \
    }                                                                        \
  }                                                                          \
  __builtin_amdgcn_s_setprio(0)

template <int EPI>
__global__ __launch_bounds__(512, 2) void big_gemm(
    const __hip_bfloat16* __restrict__ A_,
    const __hip_bfloat16* __restrict__ B_,
    const float* __restrict__ bias_,
    void* __restrict__ C_, int ldc, int K,
    const float* __restrict__ bn_g, const float* __restrict__ bn_b,
    const float* __restrict__ bn_m, const float* __restrict__ bn_v,
    const float* __restrict__ pa) {
  __shared__ __align__(16) char lds[98304];  // 3 x 32KiB A-ring
  const int tid = threadIdx.x;
  const int gx = gridDim.x;
  const int nwg = gx * gridDim.y;
  const int orig = blockIdx.y * gx + blockIdx.x;
  const int wgid = (orig & 7) * (nwg >> 3) + (orig >> 3);
  const int bx = wgid % gx;
  const int by = wgid / gx;
  const int m0 = by * 256, n0 = bx * 256;

  const int lane = tid & 63;
  const int wid = tid >> 6;
  const int wm = wid >> 2;   // 2 M-waves
  const int wn = wid & 3;    // 4 N-waves
  const int fr = lane & 15;
  const int kg = lane >> 4;

  // A staging: thread t -> row r0=t>>3 (+64/128/192), chunk c0=(t&7)^(r0&7)
  const int r0 = tid >> 3;
  const int c0 = (tid & 7) ^ (r0 & 7);
  const size_t ldb = (size_t)K * 2;
  const char* Ab = (const char*)A_ + (size_t)(m0 + r0) * ldb + c0 * 16;

  // A read: row&7 == fr&7 for all fragment rows -> per-lane consts
  const int axor0 = (kg ^ (fr & 7)) << 4;
  const int axor1 = ((4 + kg) ^ (fr & 7)) << 4;
  const char* aw = lds + (wm << 14) + fr * 128;

  auto STAGE_A = [&](int q, int u) {
    char* L = lds + q * 32768 + tid * 16;
    const char* src = Ab + (size_t)u * 128;
    gl_lds16(src, L);
    gl_lds16(src + 64 * ldb, L + 8192);
    gl_lds16(src + 128 * ldb, L + 16384);
    gl_lds16(src + 192 * ldb, L + 24576);
  };

  // B direct: per-ni pointer, advanced +128B at p1 of each tile.
  const __hip_bfloat16* bptr[4];
#pragma unroll
  for (int i = 0; i < 4; ++i)
    bptr[i] = B_ + (size_t)(n0 + wn * 64 + i * 16 + fr) * K + kg * 8;

  bf16x8 aA[4], aB[4], bA[4], bB[4];
  f32x4 acc[8][4] = {};
  const int NT = K >> 6;  // >= 3 for all users (P/FF1: 8, FF2: 32)

  // prologue: A(0)->buf0, A(1)->buf1 (8 gl_lds), B(0) both k-slices (8)
  STAGE_A(0, 0);
  STAGE_A(1, 1);
  LOADB4(bA, "0");
  LOADB4(bB, "64");
  VMC(8);  // A(0),A(1) retired; bA(0),bB(0) in flight
  __builtin_amdgcn_s_barrier();

  for (int u = 0; u < NT; ++u) {
    const int qoff = (u % 3) * 32768;
    // ---- p1 ----
    LDA_(aA, qoff, axor0, 0);
    LDA_(aB, qoff, axor0, 1);
    if (u + 2 < NT) STAGE_A((u + 2) % 3, u + 2);
#pragma unroll
    for (int i = 0; i < 4; ++i) bptr[i] += 64;  // -> tile u+1
    if (u + 2 < NT) { VMC(8); } else { VMC(0); }  // bA(u) ready
    LGKM(4);  // aA ready
    MFMAQ(0, aA, bA);
    // ---- p2 ----
    LDA_(aA, qoff, axor1, 0);
    LGKM(4);  // aB ready
    MFMAQ(1, aB, bA);
    if (u + 1 < NT) LOADB4(bA, "0");  // bA regs dead; load tile u+1 ks0
    // ---- p3 ----
    LDA_(aB, qoff, axor1, 1);
    if (u + 2 < NT) { VMC(8); } else { VMC(0); }  // bB(u) ready
    LGKM(4);  // aA(ks1) ready
    MFMAQ(0, aA, bB);
    // ---- p4 ----
    LGKM(0);  // aB(ks1) ready
    MFMAQ(1, aB, bB);
    if (u + 1 < NT) LOADB4(bB, "64");  // bB regs dead; tile u+1 ks1
    __builtin_amdgcn_s_barrier();
  }

  // epilogue: C/D layout col=lane&15, row=(lane>>4)*4+j [m89-verified]
  char* C = (char*)C_;
#pragma unroll
  for (int ni = 0; ni < 4; ++ni) {
    const int col = n0 + wn * 64 + ni * 16 + fr;
    float bcol = 0.f, scale = 0.f, shift = 0.f;
    if (EPI != EPI_BF16) bcol = bias_[col];
    if (EPI == EPI_BNPRELU) {
      scale = bn_g[col] * rsqrtf(bn_v[col] + EPSf);
      shift = bn_b[col] - bn_m[col] * scale;
    }
#pragma unroll
    for (int mi = 0; mi < 8; ++mi) {
      const int rb = m0 + wm * 128 + mi * 16 + kg * 4;
#pragma unroll
      for (int j = 0; j < 4; ++j) {
        const int row = rb + j;
        float v = acc[mi][ni][j] + bcol;
        if (EPI == EPI_F32) {
          ((float*)C)[(size_t)row * ldc + col] = v;
        } else if (EPI == EPI_BF16) {
          ((__hip_bfloat16*)C)[(size_t)row * ldc + col] = __float2bfloat16(v);
        } else {
          v = v * scale + shift;
          const float aa = pa[(size_t)(row & (Sd - 1)) * Fd + col];
          v = v > 0.f ? v : aa * v;
          ((__hip_bfloat16*)C)[(size_t)row * ldc + col] = __float2bfloat16(v);
        }
      }
    }
  }
}

// ---- m97-structure BT-GEMM (scores/PV/mha/FF3/folding) ----
template <int EPI>
__global__ __launch_bounds__(256, 2) void bt_gemm(
    const __hip_bfloat16* __restrict__ A_, int lda, size_t sA1, size_t sA2,
    const __hip_bfloat16* __restrict__ B_, int ldb, size_t sB1, size_t sB2,
    const float* __restrict__ bias_, size_t sBi1, size_t sBi2,
    void* __restrict__ C_, int ldc, size_t sC1, size_t sC2,
    int K, float alpha, int zshift,
    const float* __restrict__ bn_g, const float* __restrict__ bn_b,
    const float* __restrict__ bn_m, const float* __restrict__ bn_v,
    const float* __restrict__ pa) {
  __shared__ __hip_bfloat16 As[BM * BK];
  __shared__ __hip_bfloat16 Bs[BN * BK];

  const int tid = threadIdx.x;
  const int z = blockIdx.z;
  const int z1 = z >> zshift;
  const int z2 = z & ((1 << zshift) - 1);
  const int m0 = blockIdx.y * BM;
  const int n0 = blockIdx.x * BN;

  const __hip_bfloat16* A = A_ + (size_t)z1 * sA1 + (size_t)z2 * sA2;
  const __hip_bfloat16* Bt = B_ + (size_t)z1 * sB1 + (size_t)z2 * sB2;
  const float* bi = bias_ ? bias_ + (size_t)z1 * sBi1 + (size_t)z2 * sBi2 : nullptr;

  const int lane = tid & 63;
  const int wv = tid >> 6;
  const int wm = (wv >> 1) * 64;
  const int wn = (wv & 1) * 64;
  const int fr = lane & 15;
  const int kg = lane >> 4;

  const int srow = tid >> 2, sch = tid & 3;
  const size_t ldab = (size_t)lda * 2, ldbb = (size_t)ldb * 2;
  const char* Ap = (const char*)A + (size_t)(m0 + srow) * ldab + sch * 16;
  const char* Ap2 = Ap + 64 * ldab;
  const char* Bp = (const char*)Bt + (size_t)(n0 + srow) * ldbb + sch * 16;
  const char* Bp2 = Bp + 64 * ldbb;
  char* lA = (char*)As + tid * 16;
  char* lB = (char*)Bs + tid * 16;

  f32x4 acc[4][4] = {};

  for (int kt = 0; kt < K; kt += BK) {
    const size_t kb = (size_t)kt * 2;
    gl_lds16(Ap + kb, lA);
    gl_lds16(Ap2 + kb, lA + 4096);
    gl_lds16(Bp + kb, lB);
    gl_lds16(Bp2 + kb, lB + 4096);
    __syncthreads();

    bf16x8 afr[4], bfr[4];
#pragma unroll
    for (int mi = 0; mi < 4; ++mi)
      afr[mi] = *reinterpret_cast<const bf16x8*>(As + (wm + mi * 16 + fr) * BK + kg * 8);
#pragma unroll
    for (int ni = 0; ni < 4; ++ni)
      bfr[ni] = *reinterpret_cast<const bf16x8*>(Bs + (wn + ni * 16 + fr) * BK + kg * 8);
#pragma unroll
    for (int mi = 0; mi < 4; ++mi)
#pragma unroll
      for (int ni = 0; ni < 4; ++ni)
        acc[mi][ni] = __builtin_amdgcn_mfma_f32_16x16x32_bf16(afr[mi], bfr[ni], acc[mi][ni], 0, 0, 0);
    __syncthreads();
  }

  char* C = (char*)C_ + ((size_t)z1 * sC1 + (size_t)z2 * sC2) * ((EPI == EPI_F32) ? 4 : 2);
  const float cs = (EPI == EPI_SCORES) ? bn_m[z2] : 0.f;
  float rp[4][4];
  if (EPI == EPI_SCORES) {
#pragma unroll
    for (int mi = 0; mi < 4; ++mi)
#pragma unroll
      for (int j = 0; j < 4; ++j) rp[mi][j] = 0.f;
  }
  float rinv_[4][4];
  if (EPI == EPI_PV) {
#pragma unroll
    for (int mi = 0; mi < 4; ++mi)
#pragma unroll
      for (int j = 0; j < 4; ++j)
        rinv_[mi][j] = 1.0f / bn_v[((size_t)z << 10) + m0 + wm + mi * 16 + kg * 4 + j];
  }
#pragma unroll
  for (int ni = 0; ni < 4; ++ni) {
    const int col = n0 + wn + ni * 16 + fr;
    float bcol = 0.f, scale = 0.f, shift = 0.f;
    if (bi) bcol = bi[col];
    if (EPI == EPI_BNPRELU) {
      scale = bn_g[col] * rsqrtf(bn_v[col] + EPSf);
      shift = bn_b[col] - bn_m[col] * scale;
    }
    const float wcol = (EPI == EPI_SCORES) ? bn_b[z2 * 8192 + z1 * 1024 + col] : 0.f;
#pragma unroll
    for (int mi = 0; mi < 4; ++mi) {
      const int rb = m0 + wm + mi * 16 + kg * 4;
#pragma unroll
      for (int j = 0; j < 4; ++j) {
        const int row = rb + j;
        if (EPI == EPI_SCORES) {
          const float e = __expf((acc[mi][ni][j] + bn_g[z2 * 8192 + z1 * 1024 + row] + wcol + cs) * alpha);
          rp[mi][j] += e;
          ((__hip_bfloat16*)C)[(size_t)row * ldc + col] = __float2bfloat16(e);
        } else if (EPI == EPI_PV) {
          ((__hip_bfloat16*)C)[(size_t)row * ldc + col] = __float2bfloat16(acc[mi][ni][j] * rinv_[mi][j]);
        } else {
          float v = acc[mi][ni][j] * alpha + bcol;
          if (EPI == EPI_F32) {
            ((float*)C)[(size_t)row * ldc + col] = v;
          } else if (EPI == EPI_BF16) {
            ((__hip_bfloat16*)C)[(size_t)row * ldc + col] = __float2bfloat16(v);
          } else {
            v = v * scale + shift;
            const float a = pa[(size_t)(row & (Sd - 1)) * Fd + col];
            v = v > 0.f ? v : a * v;
            ((__hip_bfloat16*)C)[(size_t)row * ldc + col] = __float2bfloat16(v);
          }
        }
      }
    }
  }
  if (EPI == EPI_SCORES) {
    float* rs = (float*)bn_v + ((size_t)z << 10) + m0 + wm;
#pragma unroll
    for (int mi = 0; mi < 4; ++mi)
#pragma unroll
      for (int j = 0; j < 4; ++j) {
        float v = rp[mi][j];
        v += __shfl_xor(v, 1);
        v += __shfl_xor(v, 2);
        v += __shfl_xor(v, 4);
        v += __shfl_xor(v, 8);
        if (fr == 0) atomicAdd(rs + mi * 16 + kg * 4 + j, v);
      }
  }
}

// ---- transpose + convert: src [K][N] f32 -> dst [N][Kfull] bf16 ----
__global__ __launch_bounds__(256) void tconv(const float* __restrict__ src,
                                             __hip_bfloat16* __restrict__ dst,
                                             int N, int Kfull, size_t sIn, size_t sOut) {
  __shared__ __hip_bfloat16 t[64][65];
  const float* s = src + (size_t)blockIdx.z * sIn;
  __hip_bfloat16* d = dst + (size_t)blockIdx.z * sOut;
  const int k0 = blockIdx.y * 64, n0 = blockIdx.x * 64;
  const int tid = threadIdx.x;
#pragma unroll
  for (int i = 0; i < 4; ++i) {
    int slot = tid + i * 256;
    int r = slot >> 4, c = (slot & 15) * 4;
    const float4 v = *reinterpret_cast<const float4*>(s + (size_t)(k0 + r) * N + n0 + c);
    t[c + 0][r] = __float2bfloat16(v.x);
    t[c + 1][r] = __float2bfloat16(v.y);
    t[c + 2][r] = __float2bfloat16(v.z);
    t[c + 3][r] = __float2bfloat16(v.w);
  }
  __syncthreads();
#pragma unroll
  for (int i = 0; i < 2; ++i) {
    int slot = tid + i * 256;
    int n = slot >> 3, kc = (slot & 7) * 8;
    __hip_bfloat16 tmp[8];
#pragma unroll
    for (int j = 0; j < 8; ++j) tmp[j] = t[n][kc + j];
    *reinterpret_cast<float4*>(d + (size_t)(n0 + n) * Kfull + k0 + kc) =
        *reinterpret_cast<const float4*>(tmp);
  }
}

// ---- f32 -> bf16 elementwise; grid (nblk, ntensors), 8 elems/thread ----
__global__ __launch_bounds__(256) void conv3(const float* __restrict__ s0, const float* __restrict__ s1,
                                             const float* __restrict__ s2,
                                             __hip_bfloat16* __restrict__ d0, __hip_bfloat16* __restrict__ d1,
                                             __hip_bfloat16* __restrict__ d2) {
  const float* s = blockIdx.y == 0 ? s0 : (blockIdx.y == 1 ? s1 : s2);
  __hip_bfloat16* d = blockIdx.y == 0 ? d0 : (blockIdx.y == 1 ? d1 : d2);
  const size_t i = (size_t)blockIdx.x * 256 + threadIdx.x;
  const float4 a = reinterpret_cast<const float4*>(s)[2 * i];
  const float4 b = reinterpret_cast<const float4*>(s)[2 * i + 1];
  __hip_bfloat16 tmp[8] = {
      __float2bfloat16(a.x), __float2bfloat16(a.y), __float2bfloat16(a.z), __float2bfloat16(a.w),
      __float2bfloat16(b.x), __float2bfloat16(b.y), __float2bfloat16(b.z), __float2bfloat16(b.w)};
  *reinterpret_cast<float4*>(d + 8 * i) = *reinterpret_cast<const float4*>(tmp);
}

// ---- reductions ----
__device__ inline float wave_max(float v) {
#pragma unroll
  for (int o = 32; o > 0; o >>= 1) v = fmaxf(v, __shfl_xor(v, o));
  return v;
}
__device__ inline float wave_sum(float v) {
#pragma unroll
  for (int o = 32; o > 0; o >>= 1) v += __shfl_xor(v, o);
  return v;
}

__device__ inline float b2f(unsigned short u) {
  unsigned x = ((unsigned)u) << 16; float f; __builtin_memcpy(&f, &x, 4); return f;
}

// t1[hd] = sum_e WQ[h][d][e]*bK[h][e] (y=0); t2[hd] = sum_e WK[h][d][e]*bQ[h][e] (y=1)
__global__ __launch_bounds__(256) void tvec(const float* __restrict__ WQ, const float* __restrict__ bK,
                                            const float* __restrict__ WK, const float* __restrict__ bQ,
                                            float* __restrict__ t1, float* __restrict__ t2) {
  const float* W = blockIdx.y == 0 ? WQ : WK;
  const float* bb = blockIdx.y == 0 ? bK : bQ;
  float* out = blockIdx.y == 0 ? t1 : t2;
  const int wv = threadIdx.x >> 6, lane = threadIdx.x & 63;
  const int hd = blockIdx.x * 4 + wv;
  const int h = hd >> 9;
  float acc = 0.f;
#pragma unroll
  for (int j = 0; j < 8; ++j) {
    const int e = lane + 64 * j;
    acc += W[(size_t)hd * 512 + e] * bb[h * 512 + e];
  }
  acc = wave_sum(acc);
  if (lane == 0) out[hd] = acc;
}

// u[h][row] = Q[row]·t1[h], w[h][row] = K[row]·t2[h]. grid (8192), 256 thr.
__global__ __launch_bounds__(256) void uw_kernel(const float* __restrict__ Q, const float* __restrict__ K,
                                                 const float* __restrict__ t1, const float* __restrict__ t2,
                                                 float* __restrict__ u, float* __restrict__ w) {
  const int tid = threadIdx.x;
  const size_t row = blockIdx.x;
  const float2 q = reinterpret_cast<const float2*>(Q + row * 512)[tid];
  const float2 k = reinterpret_cast<const float2*>(K + row * 512)[tid];
  const int c = tid * 2;
  __shared__ float redu[8][4], redw[8][4];
  const int wv = tid >> 6;
#pragma unroll
  for (int h = 0; h < 8; ++h) {
    float ua = q.x * t1[h * 512 + c] + q.y * t1[h * 512 + c + 1];
    float wa = k.x * t2[h * 512 + c] + k.y * t2[h * 512 + c + 1];
    ua = wave_sum(ua);
    wa = wave_sum(wa);
    if ((tid & 63) == 0) { redu[h][wv] = ua; redw[h][wv] = wa; }
  }
  __syncthreads();
  if (tid < 8)
    u[tid * 8192 + row] = redu[tid][0] + redu[tid][1] + redu[tid][2] + redu[tid][3];
  else if (tid < 16)
    w[(tid - 8) * 8192 + row] = redw[tid - 8][0] + redw[tid - 8][1] + redw[tid - 8][2] + redw[tid - 8][3];
}

// c[h] = bQ[h]·bK[h]. grid (8), 256 thr.
__global__ __launch_bounds__(256) void cvec(const float* __restrict__ bQ, const float* __restrict__ bK,
                                            float* __restrict__ c) {
  const int h = blockIdx.x, tid = threadIdx.x;
  const float2 a = reinterpret_cast<const float2*>(bQ + h * 512)[tid];
  const float2 b = reinterpret_cast<const float2*>(bK + h * 512)[tid];
  float acc = wave_sum(a.x * b.x + a.y * b.y);
  __shared__ float red[4];
  if ((tid & 63) == 0) red[tid >> 6] = acc;
  __syncthreads();
  if (tid == 0) c[h] = red[0] + red[1] + red[2] + red[3];
}

// bvo[e] = bo[e] + sum_hd wot[e][hd]*bV[hd]. grid (128), 256 thr.
__global__ __launch_bounds__(256) void bvo_kernel(const __hip_bfloat16* __restrict__ wot,
                                                  const float* __restrict__ bV,
                                                  const float* __restrict__ bo,
                                                  float* __restrict__ bvo) {
  const int wv = threadIdx.x >> 6, lane = threadIdx.x & 63;
  const int e = blockIdx.x * 4 + wv;
  float acc = 0.f;
#pragma unroll
  for (int j = 0; j < 64; ++j) {
    const int hd = lane + 64 * j;
    acc += b2f(*(const unsigned short*)&wot[(size_t)e * 4096 + hd]) * bV[hd];
  }
  acc = wave_sum(acc);
  if (lane == 0) bvo[e] = bo[e] + acc;
}

// out = LN(Xa + Xb)*gamma + beta (rows of 512); optional bf16 copy. grid(8192), 256 thr.
__global__ __launch_bounds__(256) void add_ln(const float* __restrict__ Xa, const float* __restrict__ Xb,
                                              const float* __restrict__ gamma, const float* __restrict__ beta,
                                              float* __restrict__ out, __hip_bfloat16* __restrict__ outb) {
  const int tid = threadIdx.x;
  const size_t base = (size_t)blockIdx.x * Dd;
  const float2 a = reinterpret_cast<const float2*>(Xa + base)[tid];
  const float2 b = reinterpret_cast<const float2*>(Xb + base)[tid];
  const float r0 = a.x + b.x, r1 = a.y + b.y;
  float s = wave_sum(r0 + r1);
  float q = wave_sum(r0 * r0 + r1 * r1);
  __shared__ float rs[4], rq[4];
  if ((tid & 63) == 0) { rs[tid >> 6] = s; rq[tid >> 6] = q; }
  __syncthreads();
  const float mean = (rs[0] + rs[1] + rs[2] + rs[3]) * (1.f / Dd);
  const float msq = (rq[0] + rq[1] + rq[2] + rq[3]) * (1.f / Dd);
  const float inv = rsqrtf(msq - mean * mean + EPSf);
  const int c = tid * 2;
  const float y0 = (r0 - mean) * inv * gamma[c] + beta[c];
  const float y1 = (r1 - mean) * inv * gamma[c + 1] + beta[c + 1];
  out[base + c] = y0;
  out[base + c + 1] = y1;
  if (outb) {
    outb[base + c] = __float2bfloat16(y0);
    outb[base + c + 1] = __float2bfloat16(y1);
  }
}

extern "C" void kernel_launch(void* const* d_in, const int* in_sizes, int n_in,
                              void* d_out, int out_size, void* d_ws, size_t ws_size,
                              hipStream_t stream) {
  const float* Q = (const float*)d_in[0];
  const float* K = (const float*)d_in[1];
  const float* V = (const float*)d_in[2];
  const float* WQ = (const float*)d_in[3];
  const float* bQ = (const float*)d_in[4];
  const float* WK = (const float*)d_in[5];
  const float* bK = (const float*)d_in[6];
  const float* WV = (const float*)d_in[7];
  const float* bV = (const float*)d_in[8];
  const float* Wo = (const float*)d_in[9];
  const float* bo = (const float*)d_in[10];
  const float* W0 = (const float*)d_in[11];
  const float* b0 = (const float*)d_in[12];
  const float* g0 = (const float*)d_in[13];
  const float* be0 = (const float*)d_in[14];
  const float* m0 = (const float*)d_in[15];
  const float* v0 = (const float*)d_in[16];
  const float* a0 = (const float*)d_in[17];
  const float* W1 = (const float*)d_in[18];
  const float* b1 = (const float*)d_in[19];
  const float* g1 = (const float*)d_in[20];
  const float* be1 = (const float*)d_in[21];
  const float* m1 = (const float*)d_in[22];
  const float* v1 = (const float*)d_in[23];
  const float* a1 = (const float*)d_in[24];
  const float* W2 = (const float*)d_in[25];
  const float* b2 = (const float*)d_in[26];
  const float* ln0g = (const float*)d_in[27];
  const float* ln0b = (const float*)d_in[28];
  const float* ln1g = (const float*)d_in[29];
  const float* ln1b = (const float*)d_in[30];

  typedef __hip_bfloat16 bf;
  const size_t MB = 1u << 20;
  const size_t KB = 1u << 10;
  char* ws = (char*)d_ws;
  // -------- attention layout (peak 120 MiB) --------
  bf* PR = (bf*)(ws);                      // [8192][4096]  0..64M   P, then R in place
  bf* wot = (bf*)(ws + 64 * MB);           // [512][4096]   64..68M  (pre-loop only)
  bf* wqbf = (bf*)(ws + 68 * MB);          // [8][512][512] 68..72M  (pre-P)
  bf* wkbf = (bf*)(ws + 72 * MB);          // 72..76M
  bf* wvbf = (bf*)(ws + 76 * MB);          // 76..80M (used pre-loop)
  bf* wqkt = (bf*)(ws + 80 * MB);          // 80..84M (used for P only)
  bf* sc = (bf*)(ws + 64 * MB);            // [16][1024][1024] 64..96M (loop)
  bf* kbf = (bf*)(ws + 96 * MB);           // [8192][512]   96..104M
  bf* vbft = (bf*)(ws + 104 * MB);         // [8][512][1024] 104..112M
  bf* qbf = (bf*)(ws + 112 * MB);          // [8192][512]   112..120M (dead after P)
  bf* wvot = (bf*)(ws + 112 * MB);         // [512][4096]   112..116M (after P)
  float* u = (float*)(ws + 116 * MB);                 // [8][8192] 256K
  float* w = (float*)(ws + 116 * MB + 256 * KB);      // 256K
  float* rsum = (float*)(ws + 116 * MB + 512 * KB);   // [64][1024] 256K
  float* t1 = (float*)(ws + 116 * MB + 768 * KB);     // [8][512]
  float* t2 = (float*)(ws + 116 * MB + 784 * KB);
  float* cv = (float*)(ws + 116 * MB + 800 * KB);     // [8]
  float* bvo = (float*)(ws + 116 * MB + 804 * KB);    // [512]
  // -------- post-attention (dead-region reuse) --------
  float* mha = (float*)(ws + 64 * MB);     // [8192][512] f32 (over sc)
  float* xbuf = (float*)(ws + 80 * MB);    // 80..96M
  bf* xb = (bf*)(ws + 96 * MB);            // over kbf
  bf* w0t = (bf*)(ws + 104 * MB);          // over vbft
  bf* w1t = (bf*)(ws + 106 * MB);          // 106..114M (after mha; wvot dead)
  bf* w2t = (bf*)(ws + 114 * MB);          // 114..116M
  bf* h0 = (bf*)(ws);                      // [8192][2048] over PR
  bf* h1 = (bf*)(ws + 32 * MB);
  float* ff = (float*)(ws + 64 * MB);      // over mha (dead after LN0)

  const size_t SD = (size_t)Sd * Dd;       // 524288
  const size_t DD = (size_t)Dd * Dd;       // 262144
  const size_t SS = (size_t)Sd * Sd;       // 1048576
  const size_t SDH = (size_t)Sd * Hd * Dd; // 4194304
  const float* np = nullptr;

  // ---- conversions ----
  conv3<<<dim3(2048, 2), 256, 0, stream>>>(Q, K, K, qbf, kbf, kbf);
  conv3<<<dim3(1024, 3), 256, 0, stream>>>(WQ, WK, WV, wqbf, wkbf, wvbf);
  tconv<<<dim3(8, 16, 8), 256, 0, stream>>>(V, vbft, Dd, Sd, SD, SD);
  tconv<<<dim3(8, 64, 1), 256, 0, stream>>>(Wo, wot, Dd, Hd * Dd, 0, 0);

  // ---- wqkt fold + P (while qbf alive) ----
  bt_gemm<EPI_BF16><<<dim3(4, 4, 8), 256, 0, stream>>>(
      wkbf, Dd, 0, DD, wqbf, Dd, 0, DD, np, 0, 0,
      wqkt, Dd, 0, DD, Dd, 1.f, 3, np, np, np, np, np);
  big_gemm<EPI_BF16><<<dim3(16, 32), 512, 0, stream>>>(
      qbf, wqkt, np, PR, Hd * Dd, Dd, np, np, np, np, np);

  // ---- remaining precompute (qbf region now dead) ----
  bt_gemm<EPI_BF16><<<dim3(4, 4, 8), 256, 0, stream>>>(
      wot, Hd * Dd, 0, 512, wvbf, Dd, 0, DD, np, 0, 0,
      wvot, Hd * Dd, 0, 512, Dd, 1.f, 3, np, np, np, np, np);
  tvec<<<dim3(1024, 2), 256, 0, stream>>>(WQ, bK, WK, bQ, t1, t2);
  uw_kernel<<<Bd * Sd, 256, 0, stream>>>(Q, K, t1, t2, u, w);
  cvec<<<8, 256, 0, stream>>>(bQ, bK, cv);
  bvo_kernel<<<128, 256, 0, stream>>>(wot, bV, bo, bvo);
  hipMemsetAsync(rsum, 0, 64 * 1024 * sizeof(float), stream);

  // ---- attention middle: 2 batches per iteration, no softmax kernel ----
  for (int bp = 0; bp < 4; ++bp) {
    const bf* Ap = PR + (size_t)bp * 2 * SDH;
    bt_gemm<EPI_SCORES><<<dim3(8, 8, 16), 256, 0, stream>>>(
        Ap, Hd * Dd, SDH, 512, kbf + (size_t)bp * 2 * SD, Dd, SD, 0, np, 0, 0,
        sc, Sd, 8 * SS, SS, Dd, 1.f / (float)Dd, 3,
        u + bp * 2048, w + bp * 2048, cv, rsum + bp * 16384, np);
    bt_gemm<EPI_PV><<<dim3(4, 8, 16), 256, 0, stream>>>(
        sc, Sd, 8 * SS, SS, vbft + (size_t)bp * 2 * SD, Sd, SD, 0, np, 0, 0,
        (void*)Ap, Hd * Dd, SDH, 512, Sd, 1.f, 3,
        np, np, np, rsum + bp * 16384, np);
  }

  // ---- mha = Rcat @ Wvo + bvo ----
  bt_gemm<EPI_F32><<<dim3(4, 64, 1), 256, 0, stream>>>(
      PR, Hd * Dd, 0, 0, wvot, Hd * Dd, 0, 0, bvo, 0, 0,
      mha, Dd, 0, 0, Hd * Dd, 1.f, 0, np, np, np, np, np);
  add_ln<<<Bd * Sd, 256, 0, stream>>>(Q, mha, ln0g, ln0b, xbuf, xb);

  // ---- FF ----
  tconv<<<dim3(32, 8, 1), 256, 0, stream>>>(W0, w0t, Fd, Dd, 0, 0);
  tconv<<<dim3(32, 32, 1), 256, 0, stream>>>(W1, w1t, Fd, Fd, 0, 0);
  tconv<<<dim3(8, 32, 1), 256, 0, stream>>>(W2, w2t, Dd, Fd, 0, 0);

  big_gemm<EPI_BNPRELU><<<dim3(8, 32), 512, 0, stream>>>(
      xb, w0t, b0, h0, Fd, Dd, g0, be0, m0, v0, a0);
  big_gemm<EPI_BNPRELU><<<dim3(8, 32), 512, 0, stream>>>(
      h0, w1t, b1, h1, Fd, Fd, g1, be1, m1, v1, a1);
  bt_gemm<EPI_F32><<<dim3(4, 64, 1), 256, 0, stream>>>(
      h1, Fd, 0, 0, w2t, Fd, 0, 0, b2, 0, 0,
      ff, Dd, 0, 0, Fd, 1.f, 0, np, np, np, np, np);
  add_ln<<<Bd * Sd, 256, 0, stream>>>(xbuf, ff, ln1g, ln1b, (float*)d_out, nullptr);
}

// Round 10
// 698.715 us; speedup vs baseline: 1.1150x; 1.1150x over previous
//
#include <hip/hip_runtime.h>
#include <hip/hip_bf16.h>
#include <cstdint>
#include <cstddef>

#define Sd 1024
#define Dd 512
#define Hd 8
#define Fd 2048
#define Bd 8
#define EPSf 1e-3f

typedef __bf16 bf16x8 __attribute__((ext_vector_type(8)));
typedef float f32x4 __attribute__((ext_vector_type(4)));
typedef __attribute__((address_space(3))) unsigned int lds_u32;
typedef __attribute__((address_space(1))) const unsigned int gl_u32;

#define BM 128
#define BN 128
#define BK 32

enum { EPI_BF16 = 0, EPI_F32 = 1, EPI_BNPRELU = 2, EPI_SCORES = 3, EPI_PV = 4 };

__device__ __forceinline__ void gl_lds16(const void* g, void* l) {
  __builtin_amdgcn_global_load_lds((gl_u32*)g, (lds_u32*)l, 16, 0, 0);
}

// ======================================================================
// 256x256 GEMM (frozen R6 core, 674 TF class): counted-lgkmcnt pipeline.
// C[M,N] = epi(alpha * A @ Bt^T + bias). A [M,K] bf16 row-stride lda,
// Bt [N,K] bf16 row-stride K. M%256==0, N%256==0, K%64==0, NT>=2,
// grid (N/256, M/256, Z), (gx*gy)%8==0. 512 thr.
// z1 = z>>3, z2 = z&7; A += z1*sA1+z2*sA2, B += z1*sB1, C += z*sC.
// EPI_SCORES: e = exp((acc + u[row] + w[col] + cv[z2]) * alpha); writes
// bf16 e and atomically adds row sums into rsum[(z<<10)+row]
// (u = bn_g + z2*8192 + z1*1024, w = bn_b likewise, cv = bn_m, rsum = bn_v).
// ======================================================================

#define LGKM(n)                                                  \
  asm volatile("s_waitcnt lgkmcnt(" #n ")" ::: "memory");        \
  __builtin_amdgcn_sched_barrier(0)
#define VMC(n) asm volatile("s_waitcnt vmcnt(" #n ")" ::: "memory")

#define LDA_(dst, dof, xr, mh)                                               \
  _Pragma("unroll") for (int i_ = 0; i_ < 4; ++i_)                           \
      dst[i_] = *(const bf16x8*)(aw + (dof) + (xr) + (mh) * 8192 + i_ * 2048);
#define LDB_(dst, dof, xr)                                                   \
  _Pragma("unroll") for (int i_ = 0; i_ < 4; ++i_)                           \
      dst[i_] = *(const bf16x8*)(bw + (dof) + (xr) + i_ * 2048);
#define MFMAQ(q, av, bv)                                                     \
  __builtin_amdgcn_s_setprio(1);                                             \
  {                                                                          \
    _Pragma("unroll") for (int i_ = 0; i_ < 4; ++i_) {                       \
      _Pragma("unroll") for (int n_ = 0; n_ < 4; ++n_)                       \
          acc[(q) * 4 + i_][n_] = __builtin_amdgcn_mfma_f32_16x16x32_bf16(   \
              av[i_], bv[n_], acc[(q) * 4 + i_][n_], 0, 0, 0);               \
    }                                                                        \
  }                                                                          \
  __builtin_amdgcn_s_setprio(0)

template <int EPI>
__global__ __launch_bounds__(512, 2) void big_gemm(
    const __hip_bfloat16* __restrict__ A_, int lda, size_t sA1, size_t sA2,
    const __hip_bfloat16* __restrict__ B_, size_t sB1,
    const float* __restrict__ bias_,
    void* __restrict__ C_, int ldc, size_t sC, int K, float alpha,
    const float* __restrict__ bn_g, const float* __restrict__ bn_b,
    const float* __restrict__ bn_m, const float* __restrict__ bn_v,
    const float* __restrict__ pa) {
  __shared__ __align__(16) char lds[131072];
  const int tid = threadIdx.x;
  const int gx = gridDim.x;
  const int nwg = gx * gridDim.y;
  const int orig = blockIdx.y * gx + blockIdx.x;
  const int wgid = (orig & 7) * (nwg >> 3) + (orig >> 3);
  const int bx = wgid % gx;
  const int by = wgid / gx;
  const int m0 = by * 256, n0 = bx * 256;
  const int z = blockIdx.z;
  const int z1 = z >> 3, z2 = z & 7;

  const int lane = tid & 63;
  const int wid = tid >> 6;
  const int wm = wid >> 2;
  const int wn = wid & 3;
  const int fr = lane & 15;
  const int kg = lane >> 4;

  const int r0 = tid >> 3;
  const int c0 = (tid & 7) ^ (r0 & 7);
  const size_t lda2 = (size_t)lda * 2;
  const size_t ldb2 = (size_t)K * 2;
  const char* Ab = (const char*)(A_ + (size_t)z1 * sA1 + (size_t)z2 * sA2) +
                   (size_t)(m0 + r0) * lda2 + c0 * 16;
  const char* Bb = (const char*)(B_ + (size_t)z1 * sB1) + (size_t)(n0 + r0) * ldb2 + c0 * 16;

  const int axor0 = (kg ^ (fr & 7)) << 4;
  const int axor1 = ((4 + kg) ^ (fr & 7)) << 4;
  const char* aw = lds + (wm << 14) + fr * 128;
  const char* bw = lds + 32768 + ((wn >> 1) << 14) + ((wn & 1) << 13) + fr * 128;

  auto STG = [&](int nof, int H, int u) {  // H: 0=A0 1=A1 2=B0 3=B1
    char* L = lds + nof + (H << 14) + tid * 16;
    const size_t rs = (H < 2) ? lda2 : ldb2;
    const char* src = ((H < 2) ? Ab : Bb) + (size_t)((H & 1) * 128) * rs + (size_t)u * 128;
    gl_lds16(src, L);
    gl_lds16(src + 64 * rs, L + 8192);
  };

  bf16x8 aA[4], aB[4], bA[4], bB[4];
  f32x4 acc[8][4] = {};
  const int NT = K >> 6;

  STG(0, 0, 0); STG(0, 1, 0); STG(0, 2, 0); STG(0, 3, 0);
  STG(65536, 0, 1); STG(65536, 1, 1); STG(65536, 2, 1); STG(65536, 3, 1);
  VMC(8);
  __builtin_amdgcn_s_barrier();
  LDA_(aA, 0, axor0, 0);
  LDB_(bA, 0, axor0);

  for (int u = 0; u < NT; ++u) {
    const int dof = (u & 1) << 16;
    const int nof = dof ^ 65536;
    const bool stg = (u >= 1) & (u + 1 < NT);
    LDA_(aB, dof, axor0, 1);
    if (stg) { STG(nof, 0, u + 1); STG(nof, 1, u + 1); }
    LGKM(4);
    MFMAQ(0, aA, bA);
    LDA_(aA, dof, axor1, 0);
    LDB_(bB, dof, axor1);
    if (stg) { STG(nof, 2, u + 1); STG(nof, 3, u + 1); }
    LGKM(8);
    MFMAQ(1, aB, bA);
    LDA_(aB, dof, axor1, 1);
    LGKM(4);
    MFMAQ(0, aA, bB);
    LGKM(0);
    if (u + 1 < NT) {
      VMC(0);
      __builtin_amdgcn_s_barrier();
      LDA_(aA, nof, axor0, 0);
      LDB_(bA, nof, axor0);
    }
    MFMAQ(1, aB, bB);
  }

  // epilogue: C/D layout col=lane&15, row=(lane>>4)*4+j [m89-verified]
  char* C = (char*)C_ + (size_t)z * sC * ((EPI == EPI_F32) ? 4 : 2);
  if (EPI == EPI_SCORES) {
    const float cvv = bn_m[z2];
    const float* ub = bn_g + (size_t)z2 * 8192 + (size_t)z1 * 1024;
    const float* wb = bn_b + (size_t)z2 * 8192 + (size_t)z1 * 1024;
    float* rs = (float*)bn_v + ((size_t)z << 10);
    float wc[4];
#pragma unroll
    for (int ni = 0; ni < 4; ++ni) wc[ni] = wb[n0 + wn * 64 + ni * 16 + fr];
#pragma unroll
    for (int mi = 0; mi < 8; ++mi) {
      const int rb = m0 + wm * 128 + mi * 16 + kg * 4;
      float rowa[4] = {0.f, 0.f, 0.f, 0.f};
#pragma unroll
      for (int ni = 0; ni < 4; ++ni) {
        const int col = n0 + wn * 64 + ni * 16 + fr;
#pragma unroll
        for (int j = 0; j < 4; ++j) {
          const int row = rb + j;
          const float e = __expf((acc[mi][ni][j] + ub[row] + wc[ni] + cvv) * alpha);
          rowa[j] += e;
          ((__hip_bfloat16*)C)[(size_t)row * ldc + col] = __float2bfloat16(e);
        }
      }
#pragma unroll
      for (int j = 0; j < 4; ++j) {
        float v = rowa[j];
        v += __shfl_xor(v, 1);
        v += __shfl_xor(v, 2);
        v += __shfl_xor(v, 4);
        v += __shfl_xor(v, 8);
        if (fr == 0) atomicAdd(rs + rb + j, v);
      }
    }
  } else {
#pragma unroll
    for (int ni = 0; ni < 4; ++ni) {
      const int col = n0 + wn * 64 + ni * 16 + fr;
      float bcol = 0.f, scale = 0.f, shift = 0.f;
      if (EPI != EPI_BF16) bcol = bias_[col];
      if (EPI == EPI_BNPRELU) {
        scale = bn_g[col] * rsqrtf(bn_v[col] + EPSf);
        shift = bn_b[col] - bn_m[col] * scale;
      }
#pragma unroll
      for (int mi = 0; mi < 8; ++mi) {
        const int rb = m0 + wm * 128 + mi * 16 + kg * 4;
#pragma unroll
        for (int j = 0; j < 4; ++j) {
          const int row = rb + j;
          float v = acc[mi][ni][j] * alpha + bcol;
          if (EPI == EPI_F32) {
            ((float*)C)[(size_t)row * ldc + col] = v;
          } else if (EPI == EPI_BF16) {
            ((__hip_bfloat16*)C)[(size_t)row * ldc + col] = __float2bfloat16(v);
          } else {
            v = v * scale + shift;
            const float aa = pa[(size_t)(row & (Sd - 1)) * Fd + col];
            v = v > 0.f ? v : aa * v;
            ((__hip_bfloat16*)C)[(size_t)row * ldc + col] = __float2bfloat16(v);
          }
        }
      }
    }
  }
}

// ---- m97-structure BT-GEMM (PV/mha/FF3/folding) ----
template <int EPI>
__global__ __launch_bounds__(256, 2) void bt_gemm(
    const __hip_bfloat16* __restrict__ A_, int lda, size_t sA1, size_t sA2,
    const __hip_bfloat16* __restrict__ B_, int ldb, size_t sB1, size_t sB2,
    const float* __restrict__ bias_, size_t sBi1, size_t sBi2,
    void* __restrict__ C_, int ldc, size_t sC1, size_t sC2,
    int K, float alpha, int zshift,
    const float* __restrict__ bn_g, const float* __restrict__ bn_b,
    const float* __restrict__ bn_m, const float* __restrict__ bn_v,
    const float* __restrict__ pa) {
  __shared__ __hip_bfloat16 As[BM * BK];
  __shared__ __hip_bfloat16 Bs[BN * BK];

  const int tid = threadIdx.x;
  const int z = blockIdx.z;
  const int z1 = z >> zshift;
  const int z2 = z & ((1 << zshift) - 1);
  const int m0 = blockIdx.y * BM;
  const int n0 = blockIdx.x * BN;

  const __hip_bfloat16* A = A_ + (size_t)z1 * sA1 + (size_t)z2 * sA2;
  const __hip_bfloat16* Bt = B_ + (size_t)z1 * sB1 + (size_t)z2 * sB2;
  const float* bi = bias_ ? bias_ + (size_t)z1 * sBi1 + (size_t)z2 * sBi2 : nullptr;

  const int lane = tid & 63;
  const int wv = tid >> 6;
  const int wm = (wv >> 1) * 64;
  const int wn = (wv & 1) * 64;
  const int fr = lane & 15;
  const int kg = lane >> 4;

  const int srow = tid >> 2, sch = tid & 3;
  const size_t ldab = (size_t)lda * 2, ldbb = (size_t)ldb * 2;
  const char* Ap = (const char*)A + (size_t)(m0 + srow) * ldab + sch * 16;
  const char* Ap2 = Ap + 64 * ldab;
  const char* Bp = (const char*)Bt + (size_t)(n0 + srow) * ldbb + sch * 16;
  const char* Bp2 = Bp + 64 * ldbb;
  char* lA = (char*)As + tid * 16;
  char* lB = (char*)Bs + tid * 16;

  f32x4 acc[4][4] = {};

  for (int kt = 0; kt < K; kt += BK) {
    const size_t kb = (size_t)kt * 2;
    gl_lds16(Ap + kb, lA);
    gl_lds16(Ap2 + kb, lA + 4096);
    gl_lds16(Bp + kb, lB);
    gl_lds16(Bp2 + kb, lB + 4096);
    __syncthreads();

    bf16x8 afr[4], bfr[4];
#pragma unroll
    for (int mi = 0; mi < 4; ++mi)
      afr[mi] = *reinterpret_cast<const bf16x8*>(As + (wm + mi * 16 + fr) * BK + kg * 8);
#pragma unroll
    for (int ni = 0; ni < 4; ++ni)
      bfr[ni] = *reinterpret_cast<const bf16x8*>(Bs + (wn + ni * 16 + fr) * BK + kg * 8);
#pragma unroll
    for (int mi = 0; mi < 4; ++mi)
#pragma unroll
      for (int ni = 0; ni < 4; ++ni)
        acc[mi][ni] = __builtin_amdgcn_mfma_f32_16x16x32_bf16(afr[mi], bfr[ni], acc[mi][ni], 0, 0, 0);
    __syncthreads();
  }

  char* C = (char*)C_ + ((size_t)z1 * sC1 + (size_t)z2 * sC2) * ((EPI == EPI_F32) ? 4 : 2);
  float rinv_[4][4];
  if (EPI == EPI_PV) {
#pragma unroll
    for (int mi = 0; mi < 4; ++mi)
#pragma unroll
      for (int j = 0; j < 4; ++j)
        rinv_[mi][j] = 1.0f / bn_v[((size_t)z << 10) + m0 + wm + mi * 16 + kg * 4 + j];
  }
#pragma unroll
  for (int ni = 0; ni < 4; ++ni) {
    const int col = n0 + wn + ni * 16 + fr;
    float bcol = 0.f, scale = 0.f, shift = 0.f;
    if (bi) bcol = bi[col];
    if (EPI == EPI_BNPRELU) {
      scale = bn_g[col] * rsqrtf(bn_v[col] + EPSf);
      shift = bn_b[col] - bn_m[col] * scale;
    }
#pragma unroll
    for (int mi = 0; mi < 4; ++mi) {
      const int rb = m0 + wm + mi * 16 + kg * 4;
#pragma unroll
      for (int j = 0; j < 4; ++j) {
        const int row = rb + j;
        if (EPI == EPI_PV) {
          ((__hip_bfloat16*)C)[(size_t)row * ldc + col] = __float2bfloat16(acc[mi][ni][j] * rinv_[mi][j]);
        } else {
          float v = acc[mi][ni][j] * alpha + bcol;
          if (EPI == EPI_F32) {
            ((float*)C)[(size_t)row * ldc + col] = v;
          } else if (EPI == EPI_BF16) {
            ((__hip_bfloat16*)C)[(size_t)row * ldc + col] = __float2bfloat16(v);
          } else {
            v = v * scale + shift;
            const float a = pa[(size_t)(row & (Sd - 1)) * Fd + col];
            v = v > 0.f ? v : a * v;
            ((__hip_bfloat16*)C)[(size_t)row * ldc + col] = __float2bfloat16(v);
          }
        }
      }
    }
  }
}

// ---- transpose + convert: src [K][N] f32 -> dst [N][Kfull] bf16 ----
__global__ __launch_bounds__(256) void tconv(const float* __restrict__ src,
                                             __hip_bfloat16* __restrict__ dst,
                                             int N, int Kfull, size_t sIn, size_t sOut) {
  __shared__ __hip_bfloat16 t[64][65];
  const float* s = src + (size_t)blockIdx.z * sIn;
  __hip_bfloat16* d = dst + (size_t)blockIdx.z * sOut;
  const int k0 = blockIdx.y * 64, n0 = blockIdx.x * 64;
  const int tid = threadIdx.x;
#pragma unroll
  for (int i = 0; i < 4; ++i) {
    int slot = tid + i * 256;
    int r = slot >> 4, c = (slot & 15) * 4;
    const float4 v = *reinterpret_cast<const float4*>(s + (size_t)(k0 + r) * N + n0 + c);
    t[c + 0][r] = __float2bfloat16(v.x);
    t[c + 1][r] = __float2bfloat16(v.y);
    t[c + 2][r] = __float2bfloat16(v.z);
    t[c + 3][r] = __float2bfloat16(v.w);
  }
  __syncthreads();
#pragma unroll
  for (int i = 0; i < 2; ++i) {
    int slot = tid + i * 256;
    int n = slot >> 3, kc = (slot & 7) * 8;
    __hip_bfloat16 tmp[8];
#pragma unroll
    for (int j = 0; j < 8; ++j) tmp[j] = t[n][kc + j];
    *reinterpret_cast<float4*>(d + (size_t)(n0 + n) * Kfull + k0 + kc) =
        *reinterpret_cast<const float4*>(tmp);
  }
}

// ---- f32 -> bf16 elementwise; grid (nblk, ntensors), 8 elems/thread ----
__global__ __launch_bounds__(256) void conv3(const float* __restrict__ s0, const float* __restrict__ s1,
                                             const float* __restrict__ s2,
                                             __hip_bfloat16* __restrict__ d0, __hip_bfloat16* __restrict__ d1,
                                             __hip_bfloat16* __restrict__ d2) {
  const float* s = blockIdx.y == 0 ? s0 : (blockIdx.y == 1 ? s1 : s2);
  __hip_bfloat16* d = blockIdx.y == 0 ? d0 : (blockIdx.y == 1 ? d1 : d2);
  const size_t i = (size_t)blockIdx.x * 256 + threadIdx.x;
  const float4 a = reinterpret_cast<const float4*>(s)[2 * i];
  const float4 b = reinterpret_cast<const float4*>(s)[2 * i + 1];
  __hip_bfloat16 tmp[8] = {
      __float2bfloat16(a.x), __float2bfloat16(a.y), __float2bfloat16(a.z), __float2bfloat16(a.w),
      __float2bfloat16(b.x), __float2bfloat16(b.y), __float2bfloat16(b.z), __float2bfloat16(b.w)};
  *reinterpret_cast<float4*>(d + 8 * i) = *reinterpret_cast<const float4*>(tmp);
}

// ---- reductions ----
__device__ inline float wave_max(float v) {
#pragma unroll
  for (int o = 32; o > 0; o >>= 1) v = fmaxf(v, __shfl_xor(v, o));
  return v;
}
__device__ inline float wave_sum(float v) {
#pragma unroll
  for (int o = 32; o > 0; o >>= 1) v += __shfl_xor(v, o);
  return v;
}

__device__ inline float b2f(unsigned short u) {
  unsigned x = ((unsigned)u) << 16; float f; __builtin_memcpy(&f, &x, 4); return f;
}

// t1[hd] = sum_e WQ[h][d][e]*bK[h][e] (y=0); t2[hd] = sum_e WK[h][d][e]*bQ[h][e] (y=1)
__global__ __launch_bounds__(256) void tvec(const float* __restrict__ WQ, const float* __restrict__ bK,
                                            const float* __restrict__ WK, const float* __restrict__ bQ,
                                            float* __restrict__ t1, float* __restrict__ t2) {
  const float* W = blockIdx.y == 0 ? WQ : WK;
  const float* bb = blockIdx.y == 0 ? bK : bQ;
  float* out = blockIdx.y == 0 ? t1 : t2;
  const int wv = threadIdx.x >> 6, lane = threadIdx.x & 63;
  const int hd = blockIdx.x * 4 + wv;
  const int h = hd >> 9;
  float acc = 0.f;
#pragma unroll
  for (int j = 0; j < 8; ++j) {
    const int e = lane + 64 * j;
    acc += W[(size_t)hd * 512 + e] * bb[h * 512 + e];
  }
  acc = wave_sum(acc);
  if (lane == 0) out[hd] = acc;
}

// u[h][row] = Q[row]·t1[h], w[h][row] = K[row]·t2[h]. grid (8192), 256 thr.
__global__ __launch_bounds__(256) void uw_kernel(const float* __restrict__ Q, const float* __restrict__ K,
                                                 const float* __restrict__ t1, const float* __restrict__ t2,
                                                 float* __restrict__ u, float* __restrict__ w) {
  const int tid = threadIdx.x;
  const size_t row = blockIdx.x;
  const float2 q = reinterpret_cast<const float2*>(Q + row * 512)[tid];
  const float2 k = reinterpret_cast<const float2*>(K + row * 512)[tid];
  const int c = tid * 2;
  __shared__ float redu[8][4], redw[8][4];
  const int wv = tid >> 6;
#pragma unroll
  for (int h = 0; h < 8; ++h) {
    float ua = q.x * t1[h * 512 + c] + q.y * t1[h * 512 + c + 1];
    float wa = k.x * t2[h * 512 + c] + k.y * t2[h * 512 + c + 1];
    ua = wave_sum(ua);
    wa = wave_sum(wa);
    if ((tid & 63) == 0) { redu[h][wv] = ua; redw[h][wv] = wa; }
  }
  __syncthreads();
  if (tid < 8)
    u[tid * 8192 + row] = redu[tid][0] + redu[tid][1] + redu[tid][2] + redu[tid][3];
  else if (tid < 16)
    w[(tid - 8) * 8192 + row] = redw[tid - 8][0] + redw[tid - 8][1] + redw[tid - 8][2] + redw[tid - 8][3];
}

// c[h] = bQ[h]·bK[h]. grid (8), 256 thr.
__global__ __launch_bounds__(256) void cvec(const float* __restrict__ bQ, const float* __restrict__ bK,
                                            float* __restrict__ c) {
  const int h = blockIdx.x, tid = threadIdx.x;
  const float2 a = reinterpret_cast<const float2*>(bQ + h * 512)[tid];
  const float2 b = reinterpret_cast<const float2*>(bK + h * 512)[tid];
  float acc = wave_sum(a.x * b.x + a.y * b.y);
  __shared__ float red[4];
  if ((tid & 63) == 0) red[tid >> 6] = acc;
  __syncthreads();
  if (tid == 0) c[h] = red[0] + red[1] + red[2] + red[3];
}

// bvo[e] = bo[e] + sum_hd wot[e][hd]*bV[hd]. grid (128), 256 thr.
__global__ __launch_bounds__(256) void bvo_kernel(const __hip_bfloat16* __restrict__ wot,
                                                  const float* __restrict__ bV,
                                                  const float* __restrict__ bo,
                                                  float* __restrict__ bvo) {
  const int wv = threadIdx.x >> 6, lane = threadIdx.x & 63;
  const int e = blockIdx.x * 4 + wv;
  float acc = 0.f;
#pragma unroll
  for (int j = 0; j < 64; ++j) {
    const int hd = lane + 64 * j;
    acc += b2f(*(const unsigned short*)&wot[(size_t)e * 4096 + hd]) * bV[hd];
  }
  acc = wave_sum(acc);
  if (lane == 0) bvo[e] = bo[e] + acc;
}

// out = LN(Xa + Xb)*gamma + beta (rows of 512); optional bf16 copy. grid(8192), 256 thr.
__global__ __launch_bounds__(256) void add_ln(const float* __restrict__ Xa, const float* __restrict__ Xb,
                                              const float* __restrict__ gamma, const float* __restrict__ beta,
                                              float* __restrict__ out, __hip_bfloat16* __restrict__ outb) {
  const int tid = threadIdx.x;
  const size_t base = (size_t)blockIdx.x * Dd;
  const float2 a = reinterpret_cast<const float2*>(Xa + base)[tid];
  const float2 b = reinterpret_cast<const float2*>(Xb + base)[tid];
  const float r0 = a.x + b.x, r1 = a.y + b.y;
  float s = wave_sum(r0 + r1);
  float q = wave_sum(r0 * r0 + r1 * r1);
  __shared__ float rs[4], rq[4];
  if ((tid & 63) == 0) { rs[tid >> 6] = s; rq[tid >> 6] = q; }
  __syncthreads();
  const float mean = (rs[0] + rs[1] + rs[2] + rs[3]) * (1.f / Dd);
  const float msq = (rq[0] + rq[1] + rq[2] + rq[3]) * (1.f / Dd);
  const float inv = rsqrtf(msq - mean * mean + EPSf);
  const int c = tid * 2;
  const float y0 = (r0 - mean) * inv * gamma[c] + beta[c];
  const float y1 = (r1 - mean) * inv * gamma[c + 1] + beta[c + 1];
  out[base + c] = y0;
  out[base + c + 1] = y1;
  if (outb) {
    outb[base + c] = __float2bfloat16(y0);
    outb[base + c + 1] = __float2bfloat16(y1);
  }
}

extern "C" void kernel_launch(void* const* d_in, const int* in_sizes, int n_in,
                              void* d_out, int out_size, void* d_ws, size_t ws_size,
                              hipStream_t stream) {
  const float* Q = (const float*)d_in[0];
  const float* K = (const float*)d_in[1];
  const float* V = (const float*)d_in[2];
  const float* WQ = (const float*)d_in[3];
  const float* bQ = (const float*)d_in[4];
  const float* WK = (const float*)d_in[5];
  const float* bK = (const float*)d_in[6];
  const float* WV = (const float*)d_in[7];
  const float* bV = (const float*)d_in[8];
  const float* Wo = (const float*)d_in[9];
  const float* bo = (const float*)d_in[10];
  const float* W0 = (const float*)d_in[11];
  const float* b0 = (const float*)d_in[12];
  const float* g0 = (const float*)d_in[13];
  const float* be0 = (const float*)d_in[14];
  const float* m0 = (const float*)d_in[15];
  const float* v0 = (const float*)d_in[16];
  const float* a0 = (const float*)d_in[17];
  const float* W1 = (const float*)d_in[18];
  const float* b1 = (const float*)d_in[19];
  const float* g1 = (const float*)d_in[20];
  const float* be1 = (const float*)d_in[21];
  const float* m1 = (const float*)d_in[22];
  const float* v1 = (const float*)d_in[23];
  const float* a1 = (const float*)d_in[24];
  const float* W2 = (const float*)d_in[25];
  const float* b2 = (const float*)d_in[26];
  const float* ln0g = (const float*)d_in[27];
  const float* ln0b = (const float*)d_in[28];
  const float* ln1g = (const float*)d_in[29];
  const float* ln1b = (const float*)d_in[30];

  typedef __hip_bfloat16 bf;
  const size_t MB = 1u << 20;
  const size_t KB = 1u << 10;
  char* ws = (char*)d_ws;
  // -------- attention layout (peak 120 MiB) --------
  bf* PR = (bf*)(ws);                      // [8192][4096]  0..64M   P, then R in place
  bf* wot = (bf*)(ws + 64 * MB);           // [512][4096]   64..68M  (pre-loop only)
  bf* wqbf = (bf*)(ws + 68 * MB);          // [8][512][512] 68..72M  (pre-P)
  bf* wkbf = (bf*)(ws + 72 * MB);          // 72..76M
  bf* wvbf = (bf*)(ws + 76 * MB);          // 76..80M (used pre-loop)
  bf* wqkt = (bf*)(ws + 80 * MB);          // 80..84M (used for P only)
  bf* sc = (bf*)(ws + 64 * MB);            // [16][1024][1024] 64..96M (loop)
  bf* kbf = (bf*)(ws + 96 * MB);           // [8192][512]   96..104M
  bf* vbft = (bf*)(ws + 104 * MB);         // [8][512][1024] 104..112M
  bf* qbf = (bf*)(ws + 112 * MB);          // [8192][512]   112..120M (dead after P)
  bf* wvot = (bf*)(ws + 112 * MB);         // [512][4096]   112..116M (after P)
  float* u = (float*)(ws + 116 * MB);                 // [8][8192] 256K
  float* w = (float*)(ws + 116 * MB + 256 * KB);      // 256K
  float* rsum = (float*)(ws + 116 * MB + 512 * KB);   // [64][1024] 256K
  float* t1 = (float*)(ws + 116 * MB + 768 * KB);     // [8][512]
  float* t2 = (float*)(ws + 116 * MB + 784 * KB);
  float* cv = (float*)(ws + 116 * MB + 800 * KB);     // [8]
  float* bvo = (float*)(ws + 116 * MB + 804 * KB);    // [512]
  // -------- post-attention (dead-region reuse) --------
  float* mha = (float*)(ws + 64 * MB);     // [8192][512] f32 (over sc)
  float* xbuf = (float*)(ws + 80 * MB);    // 80..96M
  bf* xb = (bf*)(ws + 96 * MB);            // over kbf
  bf* w0t = (bf*)(ws + 104 * MB);          // over vbft
  bf* w1t = (bf*)(ws + 106 * MB);          // 106..114M (after mha; wvot dead)
  bf* w2t = (bf*)(ws + 114 * MB);          // 114..116M
  bf* h0 = (bf*)(ws);                      // [8192][2048] over PR
  bf* h1 = (bf*)(ws + 32 * MB);
  float* ff = (float*)(ws + 64 * MB);      // over mha (dead after LN0)

  const size_t SD = (size_t)Sd * Dd;       // 524288
  const size_t DD = (size_t)Dd * Dd;       // 262144
  const size_t SS = (size_t)Sd * Sd;       // 1048576
  const size_t SDH = (size_t)Sd * Hd * Dd; // 4194304
  const float* np = nullptr;

  // ---- conversions ----
  conv3<<<dim3(2048, 2), 256, 0, stream>>>(Q, K, K, qbf, kbf, kbf);
  conv3<<<dim3(1024, 3), 256, 0, stream>>>(WQ, WK, WV, wqbf, wkbf, wvbf);
  tconv<<<dim3(8, 16, 8), 256, 0, stream>>>(V, vbft, Dd, Sd, SD, SD);
  tconv<<<dim3(8, 64, 1), 256, 0, stream>>>(Wo, wot, Dd, Hd * Dd, 0, 0);

  // ---- wqkt fold + P (while qbf alive) ----
  bt_gemm<EPI_BF16><<<dim3(4, 4, 8), 256, 0, stream>>>(
      wkbf, Dd, 0, DD, wqbf, Dd, 0, DD, np, 0, 0,
      wqkt, Dd, 0, DD, Dd, 1.f, 3, np, np, np, np, np);
  big_gemm<EPI_BF16><<<dim3(16, 32, 1), 512, 0, stream>>>(
      qbf, Dd, 0, 0, wqkt, 0, np, PR, Hd * Dd, 0, Dd, 1.f, np, np, np, np, np);

  // ---- remaining precompute (qbf region now dead) ----
  bt_gemm<EPI_BF16><<<dim3(4, 4, 8), 256, 0, stream>>>(
      wot, Hd * Dd, 0, 512, wvbf, Dd, 0, DD, np, 0, 0,
      wvot, Hd * Dd, 0, 512, Dd, 1.f, 3, np, np, np, np, np);
  tvec<<<dim3(1024, 2), 256, 0, stream>>>(WQ, bK, WK, bQ, t1, t2);
  uw_kernel<<<Bd * Sd, 256, 0, stream>>>(Q, K, t1, t2, u, w);
  cvec<<<8, 256, 0, stream>>>(bQ, bK, cv);
  bvo_kernel<<<128, 256, 0, stream>>>(wot, bV, bo, bvo);
  hipMemsetAsync(rsum, 0, 64 * 1024 * sizeof(float), stream);

  // ---- attention middle: 2 batches/iter; scores on 256^2 core ----
  for (int bp = 0; bp < 4; ++bp) {
    const bf* Ap = PR + (size_t)bp * 2 * SDH;
    // scores: sc[z] = exp((P_bh @ K_b^T + u + w + c)/D), rowsums -> rsum (atomic)
    big_gemm<EPI_SCORES><<<dim3(4, 4, 16), 512, 0, stream>>>(
        Ap, Hd * Dd, SDH, 512, kbf + (size_t)bp * 2 * SD, SD, np,
        sc, Sd, SS, Dd, 1.f / (float)Dd,
        u + bp * 2048, w + bp * 2048, cv, rsum + bp * 16384, np);
    // PV: R = (sc @ V_b^T) * (1/rowsum), in place over P
    bt_gemm<EPI_PV><<<dim3(4, 8, 16), 256, 0, stream>>>(
        sc, Sd, 8 * SS, SS, vbft + (size_t)bp * 2 * SD, Sd, SD, 0, np, 0, 0,
        (void*)Ap, Hd * Dd, SDH, 512, Sd, 1.f, 3,
        np, np, np, rsum + bp * 16384, np);
  }

  // ---- mha = Rcat @ Wvo + bvo ----
  bt_gemm<EPI_F32><<<dim3(4, 64, 1), 256, 0, stream>>>(
      PR, Hd * Dd, 0, 0, wvot, Hd * Dd, 0, 0, bvo, 0, 0,
      mha, Dd, 0, 0, Hd * Dd, 1.f, 0, np, np, np, np, np);
  add_ln<<<Bd * Sd, 256, 0, stream>>>(Q, mha, ln0g, ln0b, xbuf, xb);

  // ---- FF ----
  tconv<<<dim3(32, 8, 1), 256, 0, stream>>>(W0, w0t, Fd, Dd, 0, 0);
  tconv<<<dim3(32, 32, 1), 256, 0, stream>>>(W1, w1t, Fd, Fd, 0, 0);
  tconv<<<dim3(8, 32, 1), 256, 0, stream>>>(W2, w2t, Dd, Fd, 0, 0);

  big_gemm<EPI_BNPRELU><<<dim3(8, 32, 1), 512, 0, stream>>>(
      xb, Dd, 0, 0, w0t, 0, b0, h0, Fd, 0, Dd, 1.f, g0, be0, m0, v0, a0);
  big_gemm<EPI_BNPRELU><<<dim3(8, 32, 1), 512, 0, stream>>>(
      h0, Fd, 0, 0, w1t, 0, b1, h1, Fd, 0, Fd, 1.f, g1, be1, m1, v1, a1);
  bt_gemm<EPI_F32><<<dim3(4, 64, 1), 256, 0, stream>>>(
      h1, Fd, 0, 0, w2t, Fd, 0, 0, b2, 0, 0,
      ff, Dd, 0, 0, Fd, 1.f, 0, np, np, np, np, np);
  add_ln<<<Bd * Sd, 256, 0, stream>>>(xbuf, ff, ln1g, ln1b, (float*)d_out, nullptr);
}

// Round 11
// 662.152 us; speedup vs baseline: 1.1765x; 1.0552x over previous
//
#include <hip/hip_runtime.h>
#include <hip/hip_bf16.h>
#include <cstdint>
#include <cstddef>

#define Sd 1024
#define Dd 512
#define Hd 8
#define Fd 2048
#define Bd 8
#define EPSf 1e-3f

typedef __bf16 bf16x8 __attribute__((ext_vector_type(8)));
typedef float f32x4 __attribute__((ext_vector_type(4)));
typedef __attribute__((address_space(3))) unsigned int lds_u32;
typedef __attribute__((address_space(1))) const unsigned int gl_u32;

#define BM 128
#define BN 128
#define BK 32

enum { EPI_BF16 = 0, EPI_F32 = 1, EPI_BNPRELU = 2, EPI_SCORES = 3, EPI_PV = 4 };

__device__ __forceinline__ void gl_lds16(const void* g, void* l) {
  __builtin_amdgcn_global_load_lds((gl_u32*)g, (lds_u32*)l, 16, 0, 0);
}

// ======================================================================
// 256x256 GEMM (frozen R6 core): counted-lgkmcnt pipeline.
// C[M,N] = epi(alpha * A @ Bt^T + bias). See R10 comments.
// ======================================================================

#define LGKM(n)                                                  \
  asm volatile("s_waitcnt lgkmcnt(" #n ")" ::: "memory");        \
  __builtin_amdgcn_sched_barrier(0)
#define VMC(n) asm volatile("s_waitcnt vmcnt(" #n ")" ::: "memory")

#define LDA_(dst, dof, xr, mh)                                               \
  _Pragma("unroll") for (int i_ = 0; i_ < 4; ++i_)                           \
      dst[i_] = *(const bf16x8*)(aw + (dof) + (xr) + (mh) * 8192 + i_ * 2048);
#define LDB_(dst, dof, xr)                                                   \
  _Pragma("unroll") for (int i_ = 0; i_ < 4; ++i_)                           \
      dst[i_] = *(const bf16x8*)(bw + (dof) + (xr) + i_ * 2048);
#define MFMAQ(q, av, bv)                                                     \
  __builtin_amdgcn_s_setprio(1);                                             \
  {                                                                          \
    _Pragma("unroll") for (int i_ = 0; i_ < 4; ++i_) {                       \
      _Pragma("unroll") for (int n_ = 0; n_ < 4; ++n_)                       \
          acc[(q) * 4 + i_][n_] = __builtin_amdgcn_mfma_f32_16x16x32_bf16(   \
              av[i_], bv[n_], acc[(q) * 4 + i_][n_], 0, 0, 0);               \
    }                                                                        \
  }                                                                          \
  __builtin_amdgcn_s_setprio(0)

template <int EPI>
__global__ __launch_bounds__(512, 2) void big_gemm(
    const __hip_bfloat16* __restrict__ A_, int lda, size_t sA1, size_t sA2,
    const __hip_bfloat16* __restrict__ B_, size_t sB1,
    const float* __restrict__ bias_,
    void* __restrict__ C_, int ldc, size_t sC, int K, float alpha,
    const float* __restrict__ bn_g, const float* __restrict__ bn_b,
    const float* __restrict__ bn_m, const float* __restrict__ bn_v,
    const float* __restrict__ pa) {
  __shared__ __align__(16) char lds[131072];
  const int tid = threadIdx.x;
  const int gx = gridDim.x;
  const int nwg = gx * gridDim.y;
  const int orig = blockIdx.y * gx + blockIdx.x;
  const int wgid = (orig & 7) * (nwg >> 3) + (orig >> 3);
  const int bx = wgid % gx;
  const int by = wgid / gx;
  const int m0 = by * 256, n0 = bx * 256;
  const int z = blockIdx.z;
  const int z1 = z >> 3, z2 = z & 7;

  const int lane = tid & 63;
  const int wid = tid >> 6;
  const int wm = wid >> 2;
  const int wn = wid & 3;
  const int fr = lane & 15;
  const int kg = lane >> 4;

  const int r0 = tid >> 3;
  const int c0 = (tid & 7) ^ (r0 & 7);
  const size_t lda2 = (size_t)lda * 2;
  const size_t ldb2 = (size_t)K * 2;
  const char* Ab = (const char*)(A_ + (size_t)z1 * sA1 + (size_t)z2 * sA2) +
                   (size_t)(m0 + r0) * lda2 + c0 * 16;
  const char* Bb = (const char*)(B_ + (size_t)z1 * sB1) + (size_t)(n0 + r0) * ldb2 + c0 * 16;

  const int axor0 = (kg ^ (fr & 7)) << 4;
  const int axor1 = ((4 + kg) ^ (fr & 7)) << 4;
  const char* aw = lds + (wm << 14) + fr * 128;
  const char* bw = lds + 32768 + ((wn >> 1) << 14) + ((wn & 1) << 13) + fr * 128;

  auto STG = [&](int nof, int H, int u) {  // H: 0=A0 1=A1 2=B0 3=B1
    char* L = lds + nof + (H << 14) + tid * 16;
    const size_t rs = (H < 2) ? lda2 : ldb2;
    const char* src = ((H < 2) ? Ab : Bb) + (size_t)((H & 1) * 128) * rs + (size_t)u * 128;
    gl_lds16(src, L);
    gl_lds16(src + 64 * rs, L + 8192);
  };

  bf16x8 aA[4], aB[4], bA[4], bB[4];
  f32x4 acc[8][4] = {};
  const int NT = K >> 6;

  STG(0, 0, 0); STG(0, 1, 0); STG(0, 2, 0); STG(0, 3, 0);
  STG(65536, 0, 1); STG(65536, 1, 1); STG(65536, 2, 1); STG(65536, 3, 1);
  VMC(8);
  __builtin_amdgcn_s_barrier();
  LDA_(aA, 0, axor0, 0);
  LDB_(bA, 0, axor0);

  for (int u = 0; u < NT; ++u) {
    const int dof = (u & 1) << 16;
    const int nof = dof ^ 65536;
    const bool stg = (u >= 1) & (u + 1 < NT);
    LDA_(aB, dof, axor0, 1);
    if (stg) { STG(nof, 0, u + 1); STG(nof, 1, u + 1); }
    LGKM(4);
    MFMAQ(0, aA, bA);
    LDA_(aA, dof, axor1, 0);
    LDB_(bB, dof, axor1);
    if (stg) { STG(nof, 2, u + 1); STG(nof, 3, u + 1); }
    LGKM(8);
    MFMAQ(1, aB, bA);
    LDA_(aB, dof, axor1, 1);
    LGKM(4);
    MFMAQ(0, aA, bB);
    LGKM(0);
    if (u + 1 < NT) {
      VMC(0);
      __builtin_amdgcn_s_barrier();
      LDA_(aA, nof, axor0, 0);
      LDB_(bA, nof, axor0);
    }
    MFMAQ(1, aB, bB);
  }

  // epilogue: C/D layout col=lane&15, row=(lane>>4)*4+j [m89-verified]
  char* C = (char*)C_ + (size_t)z * sC * ((EPI == EPI_F32) ? 4 : 2);
  if (EPI == EPI_SCORES) {
    const float cvv = bn_m[z2];
    const float* ub = bn_g + (size_t)z2 * 8192 + (size_t)z1 * 1024;
    const float* wb = bn_b + (size_t)z2 * 8192 + (size_t)z1 * 1024;
    float* rs = (float*)bn_v + ((size_t)z << 10);
    float wc[4];
#pragma unroll
    for (int ni = 0; ni < 4; ++ni) wc[ni] = wb[n0 + wn * 64 + ni * 16 + fr];
#pragma unroll
    for (int mi = 0; mi < 8; ++mi) {
      const int rb = m0 + wm * 128 + mi * 16 + kg * 4;
      float rowa[4] = {0.f, 0.f, 0.f, 0.f};
#pragma unroll
      for (int ni = 0; ni < 4; ++ni) {
        const int col = n0 + wn * 64 + ni * 16 + fr;
#pragma unroll
        for (int j = 0; j < 4; ++j) {
          const int row = rb + j;
          const float e = __expf((acc[mi][ni][j] + ub[row] + wc[ni] + cvv) * alpha);
          rowa[j] += e;
          ((__hip_bfloat16*)C)[(size_t)row * ldc + col] = __float2bfloat16(e);
        }
      }
#pragma unroll
      for (int j = 0; j < 4; ++j) {
        float v = rowa[j];
        v += __shfl_xor(v, 1);
        v += __shfl_xor(v, 2);
        v += __shfl_xor(v, 4);
        v += __shfl_xor(v, 8);
        if (fr == 0) atomicAdd(rs + rb + j, v);
      }
    }
  } else {
#pragma unroll
    for (int ni = 0; ni < 4; ++ni) {
      const int col = n0 + wn * 64 + ni * 16 + fr;
      float bcol = 0.f, scale = 0.f, shift = 0.f;
      if (EPI != EPI_BF16) bcol = bias_[col];
      if (EPI == EPI_BNPRELU) {
        scale = bn_g[col] * rsqrtf(bn_v[col] + EPSf);
        shift = bn_b[col] - bn_m[col] * scale;
      }
#pragma unroll
      for (int mi = 0; mi < 8; ++mi) {
        const int rb = m0 + wm * 128 + mi * 16 + kg * 4;
#pragma unroll
        for (int j = 0; j < 4; ++j) {
          const int row = rb + j;
          float v = acc[mi][ni][j] * alpha + bcol;
          if (EPI == EPI_F32) {
            ((float*)C)[(size_t)row * ldc + col] = v;
          } else if (EPI == EPI_BF16) {
            ((__hip_bfloat16*)C)[(size_t)row * ldc + col] = __float2bfloat16(v);
          } else {
            v = v * scale + shift;
            const float aa = pa[(size_t)(row & (Sd - 1)) * Fd + col];
            v = v > 0.f ? v : aa * v;
            ((__hip_bfloat16*)C)[(size_t)row * ldc + col] = __float2bfloat16(v);
          }
        }
      }
    }
  }
}

// ---- m97-structure BT-GEMM (PV/mha/FF3/folding) ----
template <int EPI>
__global__ __launch_bounds__(256, 2) void bt_gemm(
    const __hip_bfloat16* __restrict__ A_, int lda, size_t sA1, size_t sA2,
    const __hip_bfloat16* __restrict__ B_, int ldb, size_t sB1, size_t sB2,
    const float* __restrict__ bias_, size_t sBi1, size_t sBi2,
    void* __restrict__ C_, int ldc, size_t sC1, size_t sC2,
    int K, float alpha, int zshift,
    const float* __restrict__ bn_g, const float* __restrict__ bn_b,
    const float* __restrict__ bn_m, const float* __restrict__ bn_v,
    const float* __restrict__ pa) {
  __shared__ __hip_bfloat16 As[BM * BK];
  __shared__ __hip_bfloat16 Bs[BN * BK];

  const int tid = threadIdx.x;
  const int z = blockIdx.z;
  const int z1 = z >> zshift;
  const int z2 = z & ((1 << zshift) - 1);
  const int m0 = blockIdx.y * BM;
  const int n0 = blockIdx.x * BN;

  const __hip_bfloat16* A = A_ + (size_t)z1 * sA1 + (size_t)z2 * sA2;
  const __hip_bfloat16* Bt = B_ + (size_t)z1 * sB1 + (size_t)z2 * sB2;
  const float* bi = bias_ ? bias_ + (size_t)z1 * sBi1 + (size_t)z2 * sBi2 : nullptr;

  const int lane = tid & 63;
  const int wv = tid >> 6;
  const int wm = (wv >> 1) * 64;
  const int wn = (wv & 1) * 64;
  const int fr = lane & 15;
  const int kg = lane >> 4;

  const int srow = tid >> 2, sch = tid & 3;
  const size_t ldab = (size_t)lda * 2, ldbb = (size_t)ldb * 2;
  const char* Ap = (const char*)A + (size_t)(m0 + srow) * ldab + sch * 16;
  const char* Ap2 = Ap + 64 * ldab;
  const char* Bp = (const char*)Bt + (size_t)(n0 + srow) * ldbb + sch * 16;
  const char* Bp2 = Bp + 64 * ldbb;
  char* lA = (char*)As + tid * 16;
  char* lB = (char*)Bs + tid * 16;

  f32x4 acc[4][4] = {};

  for (int kt = 0; kt < K; kt += BK) {
    const size_t kb = (size_t)kt * 2;
    gl_lds16(Ap + kb, lA);
    gl_lds16(Ap2 + kb, lA + 4096);
    gl_lds16(Bp + kb, lB);
    gl_lds16(Bp2 + kb, lB + 4096);
    __syncthreads();

    bf16x8 afr[4], bfr[4];
#pragma unroll
    for (int mi = 0; mi < 4; ++mi)
      afr[mi] = *reinterpret_cast<const bf16x8*>(As + (wm + mi * 16 + fr) * BK + kg * 8);
#pragma unroll
    for (int ni = 0; ni < 4; ++ni)
      bfr[ni] = *reinterpret_cast<const bf16x8*>(Bs + (wn + ni * 16 + fr) * BK + kg * 8);
#pragma unroll
    for (int mi = 0; mi < 4; ++mi)
#pragma unroll
      for (int ni = 0; ni < 4; ++ni)
        acc[mi][ni] = __builtin_amdgcn_mfma_f32_16x16x32_bf16(afr[mi], bfr[ni], acc[mi][ni], 0, 0, 0);
    __syncthreads();
  }

  char* C = (char*)C_ + ((size_t)z1 * sC1 + (size_t)z2 * sC2) * ((EPI == EPI_F32) ? 4 : 2);
  float rinv_[4][4];
  if (EPI == EPI_PV) {
#pragma unroll
    for (int mi = 0; mi < 4; ++mi)
#pragma unroll
      for (int j = 0; j < 4; ++j)
        rinv_[mi][j] = 1.0f / bn_v[((size_t)z << 10) + m0 + wm + mi * 16 + kg * 4 + j];
  }
#pragma unroll
  for (int ni = 0; ni < 4; ++ni) {
    const int col = n0 + wn + ni * 16 + fr;
    float bcol = 0.f, scale = 0.f, shift = 0.f;
    if (bi) bcol = bi[col];
    if (EPI == EPI_BNPRELU) {
      scale = bn_g[col] * rsqrtf(bn_v[col] + EPSf);
      shift = bn_b[col] - bn_m[col] * scale;
    }
#pragma unroll
    for (int mi = 0; mi < 4; ++mi) {
      const int rb = m0 + wm + mi * 16 + kg * 4;
#pragma unroll
      for (int j = 0; j < 4; ++j) {
        const int row = rb + j;
        if (EPI == EPI_PV) {
          ((__hip_bfloat16*)C)[(size_t)row * ldc + col] = __float2bfloat16(acc[mi][ni][j] * rinv_[mi][j]);
        } else {
          float v = acc[mi][ni][j] * alpha + bcol;
          if (EPI == EPI_F32) {
            ((float*)C)[(size_t)row * ldc + col] = v;
          } else if (EPI == EPI_BF16) {
            ((__hip_bfloat16*)C)[(size_t)row * ldc + col] = __float2bfloat16(v);
          } else {
            v = v * scale + shift;
            const float a = pa[(size_t)(row & (Sd - 1)) * Fd + col];
            v = v > 0.f ? v : a * v;
            ((__hip_bfloat16*)C)[(size_t)row * ldc + col] = __float2bfloat16(v);
          }
        }
      }
    }
  }
}

// ---- transpose + convert: src [K][N] f32 -> dst [N][Kfull] bf16 ----
__global__ __launch_bounds__(256) void tconv(const float* __restrict__ src,
                                             __hip_bfloat16* __restrict__ dst,
                                             int N, int Kfull, size_t sIn, size_t sOut) {
  __shared__ __hip_bfloat16 t[64][65];
  const float* s = src + (size_t)blockIdx.z * sIn;
  __hip_bfloat16* d = dst + (size_t)blockIdx.z * sOut;
  const int k0 = blockIdx.y * 64, n0 = blockIdx.x * 64;
  const int tid = threadIdx.x;
#pragma unroll
  for (int i = 0; i < 4; ++i) {
    int slot = tid + i * 256;
    int r = slot >> 4, c = (slot & 15) * 4;
    const float4 v = *reinterpret_cast<const float4*>(s + (size_t)(k0 + r) * N + n0 + c);
    t[c + 0][r] = __float2bfloat16(v.x);
    t[c + 1][r] = __float2bfloat16(v.y);
    t[c + 2][r] = __float2bfloat16(v.z);
    t[c + 3][r] = __float2bfloat16(v.w);
  }
  __syncthreads();
#pragma unroll
  for (int i = 0; i < 2; ++i) {
    int slot = tid + i * 256;
    int n = slot >> 3, kc = (slot & 7) * 8;
    __hip_bfloat16 tmp[8];
#pragma unroll
    for (int j = 0; j < 8; ++j) tmp[j] = t[n][kc + j];
    *reinterpret_cast<float4*>(d + (size_t)(n0 + n) * Kfull + k0 + kc) =
        *reinterpret_cast<const float4*>(tmp);
  }
}

// ---- f32 -> bf16 elementwise; grid (nblk, ntensors), 8 elems/thread ----
__global__ __launch_bounds__(256) void conv3(const float* __restrict__ s0, const float* __restrict__ s1,
                                             const float* __restrict__ s2,
                                             __hip_bfloat16* __restrict__ d0, __hip_bfloat16* __restrict__ d1,
                                             __hip_bfloat16* __restrict__ d2) {
  const float* s = blockIdx.y == 0 ? s0 : (blockIdx.y == 1 ? s1 : s2);
  __hip_bfloat16* d = blockIdx.y == 0 ? d0 : (blockIdx.y == 1 ? d1 : d2);
  const size_t i = (size_t)blockIdx.x * 256 + threadIdx.x;
  const float4 a = reinterpret_cast<const float4*>(s)[2 * i];
  const float4 b = reinterpret_cast<const float4*>(s)[2 * i + 1];
  __hip_bfloat16 tmp[8] = {
      __float2bfloat16(a.x), __float2bfloat16(a.y), __float2bfloat16(a.z), __float2bfloat16(a.w),
      __float2bfloat16(b.x), __float2bfloat16(b.y), __float2bfloat16(b.z), __float2bfloat16(b.w)};
  *reinterpret_cast<float4*>(d + 8 * i) = *reinterpret_cast<const float4*>(tmp);
}

// ---- reductions ----
__device__ inline float wave_max(float v) {
#pragma unroll
  for (int o = 32; o > 0; o >>= 1) v = fmaxf(v, __shfl_xor(v, o));
  return v;
}
__device__ inline float wave_sum(float v) {
#pragma unroll
  for (int o = 32; o > 0; o >>= 1) v += __shfl_xor(v, o);
  return v;
}

__device__ inline float b2f(unsigned short u) {
  unsigned x = ((unsigned)u) << 16; float f; __builtin_memcpy(&f, &x, 4); return f;
}

// t1[hd] = sum_e WQ[h][d][e]*bK[h][e] (y=0); t2[hd] = sum_e WK[h][d][e]*bQ[h][e] (y=1)
__global__ __launch_bounds__(256) void tvec(const float* __restrict__ WQ, const float* __restrict__ bK,
                                            const float* __restrict__ WK, const float* __restrict__ bQ,
                                            float* __restrict__ t1, float* __restrict__ t2) {
  const float* W = blockIdx.y == 0 ? WQ : WK;
  const float* bb = blockIdx.y == 0 ? bK : bQ;
  float* out = blockIdx.y == 0 ? t1 : t2;
  const int wv = threadIdx.x >> 6, lane = threadIdx.x & 63;
  const int hd = blockIdx.x * 4 + wv;
  const int h = hd >> 9;
  float acc = 0.f;
#pragma unroll
  for (int j = 0; j < 8; ++j) {
    const int e = lane + 64 * j;
    acc += W[(size_t)hd * 512 + e] * bb[h * 512 + e];
  }
  acc = wave_sum(acc);
  if (lane == 0) out[hd] = acc;
}

// u[h][row] = Q[row]·t1[h], w[h][row] = K[row]·t2[h]. grid (8192), 256 thr.
__global__ __launch_bounds__(256) void uw_kernel(const float* __restrict__ Q, const float* __restrict__ K,
                                                 const float* __restrict__ t1, const float* __restrict__ t2,
                                                 float* __restrict__ u, float* __restrict__ w) {
  const int tid = threadIdx.x;
  const size_t row = blockIdx.x;
  const float2 q = reinterpret_cast<const float2*>(Q + row * 512)[tid];
  const float2 k = reinterpret_cast<const float2*>(K + row * 512)[tid];
  const int c = tid * 2;
  __shared__ float redu[8][4], redw[8][4];
  const int wv = tid >> 6;
#pragma unroll
  for (int h = 0; h < 8; ++h) {
    float ua = q.x * t1[h * 512 + c] + q.y * t1[h * 512 + c + 1];
    float wa = k.x * t2[h * 512 + c] + k.y * t2[h * 512 + c + 1];
    ua = wave_sum(ua);
    wa = wave_sum(wa);
    if ((tid & 63) == 0) { redu[h][wv] = ua; redw[h][wv] = wa; }
  }
  __syncthreads();
  if (tid < 8)
    u[tid * 8192 + row] = redu[tid][0] + redu[tid][1] + redu[tid][2] + redu[tid][3];
  else if (tid < 16)
    w[(tid - 8) * 8192 + row] = redw[tid - 8][0] + redw[tid - 8][1] + redw[tid - 8][2] + redw[tid - 8][3];
}

// c[h] = bQ[h]·bK[h]. grid (8), 256 thr.
__global__ __launch_bounds__(256) void cvec(const float* __restrict__ bQ, const float* __restrict__ bK,
                                            float* __restrict__ c) {
  const int h = blockIdx.x, tid = threadIdx.x;
  const float2 a = reinterpret_cast<const float2*>(bQ + h * 512)[tid];
  const float2 b = reinterpret_cast<const float2*>(bK + h * 512)[tid];
  float acc = wave_sum(a.x * b.x + a.y * b.y);
  __shared__ float red[4];
  if ((tid & 63) == 0) red[tid >> 6] = acc;
  __syncthreads();
  if (tid == 0) c[h] = red[0] + red[1] + red[2] + red[3];
}

// bvo[e] = bo[e] + sum_hd wot[e][hd]*bV[hd]. grid (128), 256 thr.
__global__ __launch_bounds__(256) void bvo_kernel(const __hip_bfloat16* __restrict__ wot,
                                                  const float* __restrict__ bV,
                                                  const float* __restrict__ bo,
                                                  float* __restrict__ bvo) {
  const int wv = threadIdx.x >> 6, lane = threadIdx.x & 63;
  const int e = blockIdx.x * 4 + wv;
  float acc = 0.f;
#pragma unroll
  for (int j = 0; j < 64; ++j) {
    const int hd = lane + 64 * j;
    acc += b2f(*(const unsigned short*)&wot[(size_t)e * 4096 + hd]) * bV[hd];
  }
  acc = wave_sum(acc);
  if (lane == 0) bvo[e] = bo[e] + acc;
}

// out = LN(Xa + Xb + Xc + cb[col])*gamma + beta (rows of 512). grid(8192), 256 thr.
__global__ __launch_bounds__(256) void add_ln3(const float* __restrict__ Xa, const float* __restrict__ Xb,
                                               const float* __restrict__ Xc, const float* __restrict__ cb,
                                               const float* __restrict__ gamma, const float* __restrict__ beta,
                                               float* __restrict__ out, __hip_bfloat16* __restrict__ outb) {
  const int tid = threadIdx.x;
  const size_t base = (size_t)blockIdx.x * Dd;
  const float2 a = reinterpret_cast<const float2*>(Xa + base)[tid];
  const float2 b = reinterpret_cast<const float2*>(Xb + base)[tid];
  const float2 c2 = reinterpret_cast<const float2*>(Xc + base)[tid];
  const int c = tid * 2;
  const float r0 = a.x + b.x + c2.x + cb[c];
  const float r1 = a.y + b.y + c2.y + cb[c + 1];
  float s = wave_sum(r0 + r1);
  float q = wave_sum(r0 * r0 + r1 * r1);
  __shared__ float rs[4], rq[4];
  if ((tid & 63) == 0) { rs[tid >> 6] = s; rq[tid >> 6] = q; }
  __syncthreads();
  const float mean = (rs[0] + rs[1] + rs[2] + rs[3]) * (1.f / Dd);
  const float msq = (rq[0] + rq[1] + rq[2] + rq[3]) * (1.f / Dd);
  const float inv = rsqrtf(msq - mean * mean + EPSf);
  const float y0 = (r0 - mean) * inv * gamma[c] + beta[c];
  const float y1 = (r1 - mean) * inv * gamma[c + 1] + beta[c + 1];
  out[base + c] = y0;
  out[base + c + 1] = y1;
  if (outb) {
    outb[base + c] = __float2bfloat16(y0);
    outb[base + c + 1] = __float2bfloat16(y1);
  }
}

extern "C" void kernel_launch(void* const* d_in, const int* in_sizes, int n_in,
                              void* d_out, int out_size, void* d_ws, size_t ws_size,
                              hipStream_t stream) {
  const float* Q = (const float*)d_in[0];
  const float* K = (const float*)d_in[1];
  const float* V = (const float*)d_in[2];
  const float* WQ = (const float*)d_in[3];
  const float* bQ = (const float*)d_in[4];
  const float* WK = (const float*)d_in[5];
  const float* bK = (const float*)d_in[6];
  const float* WV = (const float*)d_in[7];
  const float* bV = (const float*)d_in[8];
  const float* Wo = (const float*)d_in[9];
  const float* bo = (const float*)d_in[10];
  const float* W0 = (const float*)d_in[11];
  const float* b0 = (const float*)d_in[12];
  const float* g0 = (const float*)d_in[13];
  const float* be0 = (const float*)d_in[14];
  const float* m0 = (const float*)d_in[15];
  const float* v0 = (const float*)d_in[16];
  const float* a0 = (const float*)d_in[17];
  const float* W1 = (const float*)d_in[18];
  const float* b1 = (const float*)d_in[19];
  const float* g1 = (const float*)d_in[20];
  const float* be1 = (const float*)d_in[21];
  const float* m1 = (const float*)d_in[22];
  const float* v1 = (const float*)d_in[23];
  const float* a1 = (const float*)d_in[24];
  const float* W2 = (const float*)d_in[25];
  const float* b2 = (const float*)d_in[26];
  const float* ln0g = (const float*)d_in[27];
  const float* ln0b = (const float*)d_in[28];
  const float* ln1g = (const float*)d_in[29];
  const float* ln1b = (const float*)d_in[30];

  typedef __hip_bfloat16 bf;
  const size_t MB = 1u << 20;
  const size_t KB = 1u << 10;
  char* ws = (char*)d_ws;
  // -------- attention layout (peak 120 MiB) --------
  bf* PR = (bf*)(ws);                      // [8192][4096]  0..64M   P, then R in place
  bf* wot = (bf*)(ws + 64 * MB);           // [512][4096]   64..68M  (pre-loop only)
  bf* wqbf = (bf*)(ws + 68 * MB);          // [8][512][512] 68..72M  (pre-P)
  bf* wkbf = (bf*)(ws + 72 * MB);          // 72..76M
  bf* wvbf = (bf*)(ws + 76 * MB);          // 76..80M (pre-loop)
  bf* wqkt = (bf*)(ws + 80 * MB);          // 80..84M (P only)
  bf* sc = (bf*)(ws + 64 * MB);            // [16][1024][1024] 64..96M (loop)
  bf* kbf = (bf*)(ws + 96 * MB);           // [8192][512]   96..104M
  bf* vbft = (bf*)(ws + 104 * MB);         // [8][512][1024] 104..112M
  bf* qbf = (bf*)(ws + 112 * MB);          // [8192][512]   112..120M (dead after P)
  bf* wvot = (bf*)(ws + 112 * MB);         // [512][4096]   112..116M (after P)
  float* u = (float*)(ws + 116 * MB);                 // [8][8192] 256K
  float* w = (float*)(ws + 116 * MB + 256 * KB);      // 256K
  float* rsum = (float*)(ws + 116 * MB + 512 * KB);   // [64][1024] 256K
  float* t1 = (float*)(ws + 116 * MB + 768 * KB);     // [8][512]
  float* t2 = (float*)(ws + 116 * MB + 784 * KB);
  float* cv = (float*)(ws + 116 * MB + 800 * KB);     // [8]
  float* bvo = (float*)(ws + 116 * MB + 804 * KB);    // [512]
  // -------- post-attention (dead-region reuse, stream-order audited) --------
  float* mhap = (float*)(ws + 64 * MB);    // 2x[8192][512] f32 partials 64..96M (over sc)
  float* xbuf = (float*)(ws);              // [8192][512] f32  0..16M (over R, dead after mha)
  bf* xb = (bf*)(ws + 16 * MB);            // [8192][512] bf16 16..24M
  bf* h0 = (bf*)(ws + 24 * MB);            // [8192][2048] 24..56M
  bf* h1 = (bf*)(ws + 56 * MB);            // [8192][2048] 56..88M (over mhap, dead after LN0)
  float* ffp = (float*)(ws + 24 * MB);     // 2x[8192][512] f32 partials 24..56M (over h0, dead after FF2)
  bf* w0t = (bf*)(ws + 96 * MB);           // [2048][512]  96..98M  (over kbf, dead)
  bf* w1t = (bf*)(ws + 98 * MB);           // [2048][2048] 98..106M
  bf* w2t = (bf*)(ws + 106 * MB);          // [512][2048]  106..108M

  const size_t SD = (size_t)Sd * Dd;       // 524288
  const size_t DD = (size_t)Dd * Dd;       // 262144
  const size_t SS = (size_t)Sd * Sd;       // 1048576
  const size_t SDH = (size_t)Sd * Hd * Dd; // 4194304
  const float* np = nullptr;

  // ---- conversions ----
  conv3<<<dim3(2048, 2), 256, 0, stream>>>(Q, K, K, qbf, kbf, kbf);
  conv3<<<dim3(1024, 3), 256, 0, stream>>>(WQ, WK, WV, wqbf, wkbf, wvbf);
  tconv<<<dim3(8, 16, 8), 256, 0, stream>>>(V, vbft, Dd, Sd, SD, SD);
  tconv<<<dim3(8, 64, 1), 256, 0, stream>>>(Wo, wot, Dd, Hd * Dd, 0, 0);

  // ---- wqkt fold + P (while qbf alive) ----
  bt_gemm<EPI_BF16><<<dim3(4, 4, 8), 256, 0, stream>>>(
      wkbf, Dd, 0, DD, wqbf, Dd, 0, DD, np, 0, 0,
      wqkt, Dd, 0, DD, Dd, 1.f, 3, np, np, np, np, np);
  big_gemm<EPI_BF16><<<dim3(16, 32, 1), 512, 0, stream>>>(
      qbf, Dd, 0, 0, wqkt, 0, np, PR, Hd * Dd, 0, Dd, 1.f, np, np, np, np, np);

  // ---- remaining precompute (qbf region now dead) ----
  bt_gemm<EPI_BF16><<<dim3(4, 4, 8), 256, 0, stream>>>(
      wot, Hd * Dd, 0, 512, wvbf, Dd, 0, DD, np, 0, 0,
      wvot, Hd * Dd, 0, 512, Dd, 1.f, 3, np, np, np, np, np);
  tvec<<<dim3(1024, 2), 256, 0, stream>>>(WQ, bK, WK, bQ, t1, t2);
  uw_kernel<<<Bd * Sd, 256, 0, stream>>>(Q, K, t1, t2, u, w);
  cvec<<<8, 256, 0, stream>>>(bQ, bK, cv);
  bvo_kernel<<<128, 256, 0, stream>>>(wot, bV, bo, bvo);
  hipMemsetAsync(rsum, 0, 64 * 1024 * sizeof(float), stream);

  // ---- attention middle: 2 batches/iter; scores on 256^2 core ----
  for (int bp = 0; bp < 4; ++bp) {
    const bf* Ap = PR + (size_t)bp * 2 * SDH;
    big_gemm<EPI_SCORES><<<dim3(4, 4, 16), 512, 0, stream>>>(
        Ap, Hd * Dd, SDH, 512, kbf + (size_t)bp * 2 * SD, SD, np,
        sc, Sd, SS, Dd, 1.f / (float)Dd,
        u + bp * 2048, w + bp * 2048, cv, rsum + bp * 16384, np);
    bt_gemm<EPI_PV><<<dim3(4, 8, 16), 256, 0, stream>>>(
        sc, Sd, 8 * SS, SS, vbft + (size_t)bp * 2 * SD, Sd, SD, 0, np, 0, 0,
        (void*)Ap, Hd * Dd, SDH, 512, Sd, 1.f, 3,
        np, np, np, rsum + bp * 16384, np);
  }

  // ---- mha partials: split-K (z=half), p_z = Rcat[:,zK/2:] @ Wvo[:,zK/2:]^T ----
  bt_gemm<EPI_F32><<<dim3(4, 64, 2), 256, 0, stream>>>(
      PR, Hd * Dd, 2048, 0, wvot, Hd * Dd, 2048, 0, np, 0, 0,
      mhap, Dd, SDH, 0, 2048, 1.f, 0, np, np, np, np, np);
  // x = LN(Q + p0 + p1 + bvo)
  add_ln3<<<Bd * Sd, 256, 0, stream>>>(Q, mhap, mhap + SDH, bvo, ln0g, ln0b, xbuf, xb);

  // ---- FF ----
  tconv<<<dim3(32, 8, 1), 256, 0, stream>>>(W0, w0t, Fd, Dd, 0, 0);
  tconv<<<dim3(32, 32, 1), 256, 0, stream>>>(W1, w1t, Fd, Fd, 0, 0);
  tconv<<<dim3(8, 32, 1), 256, 0, stream>>>(W2, w2t, Dd, Fd, 0, 0);

  big_gemm<EPI_BNPRELU><<<dim3(8, 32, 1), 512, 0, stream>>>(
      xb, Dd, 0, 0, w0t, 0, b0, h0, Fd, 0, Dd, 1.f, g0, be0, m0, v0, a0);
  big_gemm<EPI_BNPRELU><<<dim3(8, 32, 1), 512, 0, stream>>>(
      h0, Fd, 0, 0, w1t, 0, b1, h1, Fd, 0, Fd, 1.f, g1, be1, m1, v1, a1);
  // ff partials: split-K (z=half) of h1 @ w2t^T
  bt_gemm<EPI_F32><<<dim3(4, 64, 2), 256, 0, stream>>>(
      h1, Fd, 1024, 0, w2t, Fd, 1024, 0, np, 0, 0,
      ffp, Dd, SDH, 0, 1024, 1.f, 0, np, np, np, np, np);
  // out = LN(x + f0 + f1 + b2)
  add_ln3<<<Bd * Sd, 256, 0, stream>>>(xbuf, ffp, ffp + SDH, b2, ln1g, ln1b, (float*)d_out, nullptr);
}

// Round 12
// 656.836 us; speedup vs baseline: 1.1860x; 1.0081x over previous
//
#include <hip/hip_runtime.h>
#include <hip/hip_bf16.h>
#include <cstdint>
#include <cstddef>

#define Sd 1024
#define Dd 512
#define Hd 8
#define Fd 2048
#define Bd 8
#define EPSf 1e-3f

typedef __bf16 bf16x8 __attribute__((ext_vector_type(8)));
typedef float f32x4 __attribute__((ext_vector_type(4)));
typedef __attribute__((address_space(3))) unsigned int lds_u32;
typedef __attribute__((address_space(1))) const unsigned int gl_u32;

#define BM 128
#define BN 128
#define BK 32

enum { EPI_BF16 = 0, EPI_F32 = 1, EPI_BNPRELU = 2, EPI_SCORES = 3, EPI_PV = 4 };

__device__ __forceinline__ void gl_lds16(const void* g, void* l) {
  __builtin_amdgcn_global_load_lds((gl_u32*)g, (lds_u32*)l, 16, 0, 0);
}

// ======================================================================
// 256x256 GEMM (frozen R6 core): counted-lgkmcnt pipeline.
// C[M,N] = epi(alpha * A @ Bt^T + bias). See R10 comments.
// EPI_SCORES adds z-slice->XCD affinity: id&7 picks XCD, each XCD owns
// z in {xcd, xcd+8} sequentially (slice working set ~2MiB fits XCD L2).
// ======================================================================

#define LGKM(n)                                                  \
  asm volatile("s_waitcnt lgkmcnt(" #n ")" ::: "memory");        \
  __builtin_amdgcn_sched_barrier(0)
#define VMC(n) asm volatile("s_waitcnt vmcnt(" #n ")" ::: "memory")

#define LDA_(dst, dof, xr, mh)                                               \
  _Pragma("unroll") for (int i_ = 0; i_ < 4; ++i_)                           \
      dst[i_] = *(const bf16x8*)(aw + (dof) + (xr) + (mh) * 8192 + i_ * 2048);
#define LDB_(dst, dof, xr)                                                   \
  _Pragma("unroll") for (int i_ = 0; i_ < 4; ++i_)                           \
      dst[i_] = *(const bf16x8*)(bw + (dof) + (xr) + i_ * 2048);
#define MFMAQ(q, av, bv)                                                     \
  __builtin_amdgcn_s_setprio(1);                                             \
  {                                                                          \
    _Pragma("unroll") for (int i_ = 0; i_ < 4; ++i_) {                       \
      _Pragma("unroll") for (int n_ = 0; n_ < 4; ++n_)                       \
          acc[(q) * 4 + i_][n_] = __builtin_amdgcn_mfma_f32_16x16x32_bf16(   \
              av[i_], bv[n_], acc[(q) * 4 + i_][n_], 0, 0, 0);               \
    }                                                                        \
  }                                                                          \
  __builtin_amdgcn_s_setprio(0)

template <int EPI>
__global__ __launch_bounds__(512, 2) void big_gemm(
    const __hip_bfloat16* __restrict__ A_, int lda, size_t sA1, size_t sA2,
    const __hip_bfloat16* __restrict__ B_, size_t sB1,
    const float* __restrict__ bias_,
    void* __restrict__ C_, int ldc, size_t sC, int K, float alpha,
    const float* __restrict__ bn_g, const float* __restrict__ bn_b,
    const float* __restrict__ bn_m, const float* __restrict__ bn_v,
    const float* __restrict__ pa) {
  __shared__ __align__(16) char lds[131072];
  const int tid = threadIdx.x;
  const int gx = gridDim.x;
  int bx, by, z;
  if (EPI == EPI_SCORES) {
    // z-slice -> XCD affinity (gz % 8 == 0 required; scores gz=16)
    const int id = blockIdx.x + gx * (blockIdx.y + gridDim.y * blockIdx.z);
    const int bps = gx * gridDim.y;            // blocks per z-slice
    const int xcd = id & 7, slot = id >> 3;
    const int sl = slot / bps, inner = slot % bps;
    z = xcd + 8 * sl;
    bx = inner % gx;
    by = inner / gx;
  } else {
    const int nwg = gx * gridDim.y;
    const int orig = blockIdx.y * gx + blockIdx.x;
    const int wgid = (orig & 7) * (nwg >> 3) + (orig >> 3);
    bx = wgid % gx;
    by = wgid / gx;
    z = blockIdx.z;
  }
  const int m0 = by * 256, n0 = bx * 256;
  const int z1 = z >> 3, z2 = z & 7;

  const int lane = tid & 63;
  const int wid = tid >> 6;
  const int wm = wid >> 2;
  const int wn = wid & 3;
  const int fr = lane & 15;
  const int kg = lane >> 4;

  const int r0 = tid >> 3;
  const int c0 = (tid & 7) ^ (r0 & 7);
  const size_t lda2 = (size_t)lda * 2;
  const size_t ldb2 = (size_t)K * 2;
  const char* Ab = (const char*)(A_ + (size_t)z1 * sA1 + (size_t)z2 * sA2) +
                   (size_t)(m0 + r0) * lda2 + c0 * 16;
  const char* Bb = (const char*)(B_ + (size_t)z1 * sB1) + (size_t)(n0 + r0) * ldb2 + c0 * 16;

  const int axor0 = (kg ^ (fr & 7)) << 4;
  const int axor1 = ((4 + kg) ^ (fr & 7)) << 4;
  const char* aw = lds + (wm << 14) + fr * 128;
  const char* bw = lds + 32768 + ((wn >> 1) << 14) + ((wn & 1) << 13) + fr * 128;

  auto STG = [&](int nof, int H, int u) {  // H: 0=A0 1=A1 2=B0 3=B1
    char* L = lds + nof + (H << 14) + tid * 16;
    const size_t rs = (H < 2) ? lda2 : ldb2;
    const char* src = ((H < 2) ? Ab : Bb) + (size_t)((H & 1) * 128) * rs + (size_t)u * 128;
    gl_lds16(src, L);
    gl_lds16(src + 64 * rs, L + 8192);
  };

  bf16x8 aA[4], aB[4], bA[4], bB[4];
  f32x4 acc[8][4] = {};
  const int NT = K >> 6;

  STG(0, 0, 0); STG(0, 1, 0); STG(0, 2, 0); STG(0, 3, 0);
  STG(65536, 0, 1); STG(65536, 1, 1); STG(65536, 2, 1); STG(65536, 3, 1);
  VMC(8);
  __builtin_amdgcn_s_barrier();
  LDA_(aA, 0, axor0, 0);
  LDB_(bA, 0, axor0);

  for (int u = 0; u < NT; ++u) {
    const int dof = (u & 1) << 16;
    const int nof = dof ^ 65536;
    const bool stg = (u >= 1) & (u + 1 < NT);
    LDA_(aB, dof, axor0, 1);
    if (stg) { STG(nof, 0, u + 1); STG(nof, 1, u + 1); }
    LGKM(4);
    MFMAQ(0, aA, bA);
    LDA_(aA, dof, axor1, 0);
    LDB_(bB, dof, axor1);
    if (stg) { STG(nof, 2, u + 1); STG(nof, 3, u + 1); }
    LGKM(8);
    MFMAQ(1, aB, bA);
    LDA_(aB, dof, axor1, 1);
    LGKM(4);
    MFMAQ(0, aA, bB);
    LGKM(0);
    if (u + 1 < NT) {
      VMC(0);
      __builtin_amdgcn_s_barrier();
      LDA_(aA, nof, axor0, 0);
      LDB_(bA, nof, axor0);
    }
    MFMAQ(1, aB, bB);
  }

  // epilogue: C/D layout col=lane&15, row=(lane>>4)*4+j [m89-verified]
  char* C = (char*)C_ + (size_t)z * sC * ((EPI == EPI_F32) ? 4 : 2);
  if (EPI == EPI_SCORES) {
    const float cvv = bn_m[z2];
    const float* ub = bn_g + (size_t)z2 * 8192 + (size_t)z1 * 1024;
    const float* wb = bn_b + (size_t)z2 * 8192 + (size_t)z1 * 1024;
    float* rs = (float*)bn_v + ((size_t)z << 10);
    float wc[4];
#pragma unroll
    for (int ni = 0; ni < 4; ++ni) wc[ni] = wb[n0 + wn * 64 + ni * 16 + fr];
#pragma unroll
    for (int mi = 0; mi < 8; ++mi) {
      const int rb = m0 + wm * 128 + mi * 16 + kg * 4;
      float rowa[4] = {0.f, 0.f, 0.f, 0.f};
#pragma unroll
      for (int ni = 0; ni < 4; ++ni) {
        const int col = n0 + wn * 64 + ni * 16 + fr;
#pragma unroll
        for (int j = 0; j < 4; ++j) {
          const int row = rb + j;
          const float e = __expf((acc[mi][ni][j] + ub[row] + wc[ni] + cvv) * alpha);
          rowa[j] += e;
          ((__hip_bfloat16*)C)[(size_t)row * ldc + col] = __float2bfloat16(e);
        }
      }
#pragma unroll
      for (int j = 0; j < 4; ++j) {
        float v = rowa[j];
        v += __shfl_xor(v, 1);
        v += __shfl_xor(v, 2);
        v += __shfl_xor(v, 4);
        v += __shfl_xor(v, 8);
        if (fr == 0) atomicAdd(rs + rb + j, v);
      }
    }
  } else {
#pragma unroll
    for (int ni = 0; ni < 4; ++ni) {
      const int col = n0 + wn * 64 + ni * 16 + fr;
      float bcol = 0.f, scale = 0.f, shift = 0.f;
      if (EPI != EPI_BF16) bcol = bias_[col];
      if (EPI == EPI_BNPRELU) {
        scale = bn_g[col] * rsqrtf(bn_v[col] + EPSf);
        shift = bn_b[col] - bn_m[col] * scale;
      }
#pragma unroll
      for (int mi = 0; mi < 8; ++mi) {
        const int rb = m0 + wm * 128 + mi * 16 + kg * 4;
#pragma unroll
        for (int j = 0; j < 4; ++j) {
          const int row = rb + j;
          float v = acc[mi][ni][j] * alpha + bcol;
          if (EPI == EPI_F32) {
            ((float*)C)[(size_t)row * ldc + col] = v;
          } else if (EPI == EPI_BF16) {
            ((__hip_bfloat16*)C)[(size_t)row * ldc + col] = __float2bfloat16(v);
          } else {
            v = v * scale + shift;
            const float aa = pa[(size_t)(row & (Sd - 1)) * Fd + col];
            v = v > 0.f ? v : aa * v;
            ((__hip_bfloat16*)C)[(size_t)row * ldc + col] = __float2bfloat16(v);
          }
        }
      }
    }
  }
}

// ---- m97-structure BT-GEMM (PV/mha/FF3/folding) ----
// XCDZ=1: z-slice->XCD affinity block remap (requires gz%8==0).
template <int EPI, int XCDZ = 0>
__global__ __launch_bounds__(256, 2) void bt_gemm(
    const __hip_bfloat16* __restrict__ A_, int lda, size_t sA1, size_t sA2,
    const __hip_bfloat16* __restrict__ B_, int ldb, size_t sB1, size_t sB2,
    const float* __restrict__ bias_, size_t sBi1, size_t sBi2,
    void* __restrict__ C_, int ldc, size_t sC1, size_t sC2,
    int K, float alpha, int zshift,
    const float* __restrict__ bn_g, const float* __restrict__ bn_b,
    const float* __restrict__ bn_m, const float* __restrict__ bn_v,
    const float* __restrict__ pa) {
  __shared__ __hip_bfloat16 As[BM * BK];
  __shared__ __hip_bfloat16 Bs[BN * BK];

  const int tid = threadIdx.x;
  int bxq, byq, z;
  if (XCDZ) {
    const int gx = gridDim.x;
    const int id = blockIdx.x + gx * (blockIdx.y + gridDim.y * blockIdx.z);
    const int bps = gx * gridDim.y;
    const int xcd = id & 7, slot = id >> 3;
    const int sl = slot / bps, inner = slot % bps;
    z = xcd + 8 * sl;
    bxq = inner % gx;
    byq = inner / gx;
  } else {
    bxq = blockIdx.x;
    byq = blockIdx.y;
    z = blockIdx.z;
  }
  const int z1 = z >> zshift;
  const int z2 = z & ((1 << zshift) - 1);
  const int m0 = byq * BM;
  const int n0 = bxq * BN;

  const __hip_bfloat16* A = A_ + (size_t)z1 * sA1 + (size_t)z2 * sA2;
  const __hip_bfloat16* Bt = B_ + (size_t)z1 * sB1 + (size_t)z2 * sB2;
  const float* bi = bias_ ? bias_ + (size_t)z1 * sBi1 + (size_t)z2 * sBi2 : nullptr;

  const int lane = tid & 63;
  const int wv = tid >> 6;
  const int wm = (wv >> 1) * 64;
  const int wn = (wv & 1) * 64;
  const int fr = lane & 15;
  const int kg = lane >> 4;

  const int srow = tid >> 2, sch = tid & 3;
  const size_t ldab = (size_t)lda * 2, ldbb = (size_t)ldb * 2;
  const char* Ap = (const char*)A + (size_t)(m0 + srow) * ldab + sch * 16;
  const char* Ap2 = Ap + 64 * ldab;
  const char* Bp = (const char*)Bt + (size_t)(n0 + srow) * ldbb + sch * 16;
  const char* Bp2 = Bp + 64 * ldbb;
  char* lA = (char*)As + tid * 16;
  char* lB = (char*)Bs + tid * 16;

  f32x4 acc[4][4] = {};

  for (int kt = 0; kt < K; kt += BK) {
    const size_t kb = (size_t)kt * 2;
    gl_lds16(Ap + kb, lA);
    gl_lds16(Ap2 + kb, lA + 4096);
    gl_lds16(Bp + kb, lB);
    gl_lds16(Bp2 + kb, lB + 4096);
    __syncthreads();

    bf16x8 afr[4], bfr[4];
#pragma unroll
    for (int mi = 0; mi < 4; ++mi)
      afr[mi] = *reinterpret_cast<const bf16x8*>(As + (wm + mi * 16 + fr) * BK + kg * 8);
#pragma unroll
    for (int ni = 0; ni < 4; ++ni)
      bfr[ni] = *reinterpret_cast<const bf16x8*>(Bs + (wn + ni * 16 + fr) * BK + kg * 8);
#pragma unroll
    for (int mi = 0; mi < 4; ++mi)
#pragma unroll
      for (int ni = 0; ni < 4; ++ni)
        acc[mi][ni] = __builtin_amdgcn_mfma_f32_16x16x32_bf16(afr[mi], bfr[ni], acc[mi][ni], 0, 0, 0);
    __syncthreads();
  }

  char* C = (char*)C_ + ((size_t)z1 * sC1 + (size_t)z2 * sC2) * ((EPI == EPI_F32) ? 4 : 2);
  float rinv_[4][4];
  if (EPI == EPI_PV) {
#pragma unroll
    for (int mi = 0; mi < 4; ++mi)
#pragma unroll
      for (int j = 0; j < 4; ++j)
        rinv_[mi][j] = 1.0f / bn_v[((size_t)z << 10) + m0 + wm + mi * 16 + kg * 4 + j];
  }
#pragma unroll
  for (int ni = 0; ni < 4; ++ni) {
    const int col = n0 + wn + ni * 16 + fr;
    float bcol = 0.f, scale = 0.f, shift = 0.f;
    if (bi) bcol = bi[col];
    if (EPI == EPI_BNPRELU) {
      scale = bn_g[col] * rsqrtf(bn_v[col] + EPSf);
      shift = bn_b[col] - bn_m[col] * scale;
    }
#pragma unroll
    for (int mi = 0; mi < 4; ++mi) {
      const int rb = m0 + wm + mi * 16 + kg * 4;
#pragma unroll
      for (int j = 0; j < 4; ++j) {
        const int row = rb + j;
        if (EPI == EPI_PV) {
          ((__hip_bfloat16*)C)[(size_t)row * ldc + col] = __float2bfloat16(acc[mi][ni][j] * rinv_[mi][j]);
        } else {
          float v = acc[mi][ni][j] * alpha + bcol;
          if (EPI == EPI_F32) {
            ((float*)C)[(size_t)row * ldc + col] = v;
          } else if (EPI == EPI_BF16) {
            ((__hip_bfloat16*)C)[(size_t)row * ldc + col] = __float2bfloat16(v);
          } else {
            v = v * scale + shift;
            const float a = pa[(size_t)(row & (Sd - 1)) * Fd + col];
            v = v > 0.f ? v : a * v;
            ((__hip_bfloat16*)C)[(size_t)row * ldc + col] = __float2bfloat16(v);
          }
        }
      }
    }
  }
}

// ---- transpose + convert: src [K][N] f32 -> dst [N][Kfull] bf16 ----
__global__ __launch_bounds__(256) void tconv(const float* __restrict__ src,
                                             __hip_bfloat16* __restrict__ dst,
                                             int N, int Kfull, size_t sIn, size_t sOut) {
  __shared__ __hip_bfloat16 t[64][65];
  const float* s = src + (size_t)blockIdx.z * sIn;
  __hip_bfloat16* d = dst + (size_t)blockIdx.z * sOut;
  const int k0 = blockIdx.y * 64, n0 = blockIdx.x * 64;
  const int tid = threadIdx.x;
#pragma unroll
  for (int i = 0; i < 4; ++i) {
    int slot = tid + i * 256;
    int r = slot >> 4, c = (slot & 15) * 4;
    const float4 v = *reinterpret_cast<const float4*>(s + (size_t)(k0 + r) * N + n0 + c);
    t[c + 0][r] = __float2bfloat16(v.x);
    t[c + 1][r] = __float2bfloat16(v.y);
    t[c + 2][r] = __float2bfloat16(v.z);
    t[c + 3][r] = __float2bfloat16(v.w);
  }
  __syncthreads();
#pragma unroll
  for (int i = 0; i < 2; ++i) {
    int slot = tid + i * 256;
    int n = slot >> 3, kc = (slot & 7) * 8;
    __hip_bfloat16 tmp[8];
#pragma unroll
    for (int j = 0; j < 8; ++j) tmp[j] = t[n][kc + j];
    *reinterpret_cast<float4*>(d + (size_t)(n0 + n) * Kfull + k0 + kc) =
        *reinterpret_cast<const float4*>(tmp);
  }
}

// ---- f32 -> bf16 elementwise; grid (nblk, ntensors), 8 elems/thread ----
__global__ __launch_bounds__(256) void conv3(const float* __restrict__ s0, const float* __restrict__ s1,
                                             const float* __restrict__ s2,
                                             __hip_bfloat16* __restrict__ d0, __hip_bfloat16* __restrict__ d1,
                                             __hip_bfloat16* __restrict__ d2) {
  const float* s = blockIdx.y == 0 ? s0 : (blockIdx.y == 1 ? s1 : s2);
  __hip_bfloat16* d = blockIdx.y == 0 ? d0 : (blockIdx.y == 1 ? d1 : d2);
  const size_t i = (size_t)blockIdx.x * 256 + threadIdx.x;
  const float4 a = reinterpret_cast<const float4*>(s)[2 * i];
  const float4 b = reinterpret_cast<const float4*>(s)[2 * i + 1];
  __hip_bfloat16 tmp[8] = {
      __float2bfloat16(a.x), __float2bfloat16(a.y), __float2bfloat16(a.z), __float2bfloat16(a.w),
      __float2bfloat16(b.x), __float2bfloat16(b.y), __float2bfloat16(b.z), __float2bfloat16(b.w)};
  *reinterpret_cast<float4*>(d + 8 * i) = *reinterpret_cast<const float4*>(tmp);
}

// ---- reductions ----
__device__ inline float wave_sum(float v) {
#pragma unroll
  for (int o = 32; o > 0; o >>= 1) v += __shfl_xor(v, o);
  return v;
}

__device__ inline float b2f(unsigned short u) {
  unsigned x = ((unsigned)u) << 16; float f; __builtin_memcpy(&f, &x, 4); return f;
}

// t1[hd] = sum_e WQ[h][d][e]*bK[h][e] (y=0); t2[hd] = sum_e WK[h][d][e]*bQ[h][e] (y=1)
__global__ __launch_bounds__(256) void tvec(const float* __restrict__ WQ, const float* __restrict__ bK,
                                            const float* __restrict__ WK, const float* __restrict__ bQ,
                                            float* __restrict__ t1, float* __restrict__ t2) {
  const float* W = blockIdx.y == 0 ? WQ : WK;
  const float* bb = blockIdx.y == 0 ? bK : bQ;
  float* out = blockIdx.y == 0 ? t1 : t2;
  const int wv = threadIdx.x >> 6, lane = threadIdx.x & 63;
  const int hd = blockIdx.x * 4 + wv;
  const int h = hd >> 9;
  float acc = 0.f;
#pragma unroll
  for (int j = 0; j < 8; ++j) {
    const int e = lane + 64 * j;
    acc += W[(size_t)hd * 512 + e] * bb[h * 512 + e];
  }
  acc = wave_sum(acc);
  if (lane == 0) out[hd] = acc;
}

// u[h][row] = Q[row]·t1[h], w[h][row] = K[row]·t2[h]. grid (8192), 256 thr.
__global__ __launch_bounds__(256) void uw_kernel(const float* __restrict__ Q, const float* __restrict__ K,
                                                 const float* __restrict__ t1, const float* __restrict__ t2,
                                                 float* __restrict__ u, float* __restrict__ w) {
  const int tid = threadIdx.x;
  const size_t row = blockIdx.x;
  const float2 q = reinterpret_cast<const float2*>(Q + row * 512)[tid];
  const float2 k = reinterpret_cast<const float2*>(K + row * 512)[tid];
  const int c = tid * 2;
  __shared__ float redu[8][4], redw[8][4];
  const int wv = tid >> 6;
#pragma unroll
  for (int h = 0; h < 8; ++h) {
    float ua = q.x * t1[h * 512 + c] + q.y * t1[h * 512 + c + 1];
    float wa = k.x * t2[h * 512 + c] + k.y * t2[h * 512 + c + 1];
    ua = wave_sum(ua);
    wa = wave_sum(wa);
    if ((tid & 63) == 0) { redu[h][wv] = ua; redw[h][wv] = wa; }
  }
  __syncthreads();
  if (tid < 8)
    u[tid * 8192 + row] = redu[tid][0] + redu[tid][1] + redu[tid][2] + redu[tid][3];
  else if (tid < 16)
    w[(tid - 8) * 8192 + row] = redw[tid - 8][0] + redw[tid - 8][1] + redw[tid - 8][2] + redw[tid - 8][3];
}

// c[h] = bQ[h]·bK[h]. grid (8), 256 thr.
__global__ __launch_bounds__(256) void cvec(const float* __restrict__ bQ, const float* __restrict__ bK,
                                            float* __restrict__ c) {
  const int h = blockIdx.x, tid = threadIdx.x;
  const float2 a = reinterpret_cast<const float2*>(bQ + h * 512)[tid];
  const float2 b = reinterpret_cast<const float2*>(bK + h * 512)[tid];
  float acc = wave_sum(a.x * b.x + a.y * b.y);
  __shared__ float red[4];
  if ((tid & 63) == 0) red[tid >> 6] = acc;
  __syncthreads();
  if (tid == 0) c[h] = red[0] + red[1] + red[2] + red[3];
}

// bvo[e] = bo[e] + sum_hd wot[e][hd]*bV[hd]. grid (128), 256 thr.
__global__ __launch_bounds__(256) void bvo_kernel(const __hip_bfloat16* __restrict__ wot,
                                                  const float* __restrict__ bV,
                                                  const float* __restrict__ bo,
                                                  float* __restrict__ bvo) {
  const int wv = threadIdx.x >> 6, lane = threadIdx.x & 63;
  const int e = blockIdx.x * 4 + wv;
  float acc = 0.f;
#pragma unroll
  for (int j = 0; j < 64; ++j) {
    const int hd = lane + 64 * j;
    acc += b2f(*(const unsigned short*)&wot[(size_t)e * 4096 + hd]) * bV[hd];
  }
  acc = wave_sum(acc);
  if (lane == 0) bvo[e] = bo[e] + acc;
}

// out = LN(Xa + Xb + Xc + cb[col])*gamma + beta (rows of 512). grid(8192), 256 thr.
__global__ __launch_bounds__(256) void add_ln3(const float* __restrict__ Xa, const float* __restrict__ Xb,
                                               const float* __restrict__ Xc, const float* __restrict__ cb,
                                               const float* __restrict__ gamma, const float* __restrict__ beta,
                                               float* __restrict__ out, __hip_bfloat16* __restrict__ outb) {
  const int tid = threadIdx.x;
  const size_t base = (size_t)blockIdx.x * Dd;
  const float2 a = reinterpret_cast<const float2*>(Xa + base)[tid];
  const float2 b = reinterpret_cast<const float2*>(Xb + base)[tid];
  const float2 c2 = reinterpret_cast<const float2*>(Xc + base)[tid];
  const int c = tid * 2;
  const float r0 = a.x + b.x + c2.x + cb[c];
  const float r1 = a.y + b.y + c2.y + cb[c + 1];
  float s = wave_sum(r0 + r1);
  float q = wave_sum(r0 * r0 + r1 * r1);
  __shared__ float rs[4], rq[4];
  if ((tid & 63) == 0) { rs[tid >> 6] = s; rq[tid >> 6] = q; }
  __syncthreads();
  const float mean = (rs[0] + rs[1] + rs[2] + rs[3]) * (1.f / Dd);
  const float msq = (rq[0] + rq[1] + rq[2] + rq[3]) * (1.f / Dd);
  const float inv = rsqrtf(msq - mean * mean + EPSf);
  const float y0 = (r0 - mean) * inv * gamma[c] + beta[c];
  const float y1 = (r1 - mean) * inv * gamma[c + 1] + beta[c + 1];
  out[base + c] = y0;
  out[base + c + 1] = y1;
  if (outb) {
    outb[base + c] = __float2bfloat16(y0);
    outb[base + c + 1] = __float2bfloat16(y1);
  }
}

extern "C" void kernel_launch(void* const* d_in, const int* in_sizes, int n_in,
                              void* d_out, int out_size, void* d_ws, size_t ws_size,
                              hipStream_t stream) {
  const float* Q = (const float*)d_in[0];
  const float* K = (const float*)d_in[1];
  const float* V = (const float*)d_in[2];
  const float* WQ = (const float*)d_in[3];
  const float* bQ = (const float*)d_in[4];
  const float* WK = (const float*)d_in[5];
  const float* bK = (const float*)d_in[6];
  const float* WV = (const float*)d_in[7];
  const float* bV = (const float*)d_in[8];
  const float* Wo = (const float*)d_in[9];
  const float* bo = (const float*)d_in[10];
  const float* W0 = (const float*)d_in[11];
  const float* b0 = (const float*)d_in[12];
  const float* g0 = (const float*)d_in[13];
  const float* be0 = (const float*)d_in[14];
  const float* m0 = (const float*)d_in[15];
  const float* v0 = (const float*)d_in[16];
  const float* a0 = (const float*)d_in[17];
  const float* W1 = (const float*)d_in[18];
  const float* b1 = (const float*)d_in[19];
  const float* g1 = (const float*)d_in[20];
  const float* be1 = (const float*)d_in[21];
  const float* m1 = (const float*)d_in[22];
  const float* v1 = (const float*)d_in[23];
  const float* a1 = (const float*)d_in[24];
  const float* W2 = (const float*)d_in[25];
  const float* b2 = (const float*)d_in[26];
  const float* ln0g = (const float*)d_in[27];
  const float* ln0b = (const float*)d_in[28];
  const float* ln1g = (const float*)d_in[29];
  const float* ln1b = (const float*)d_in[30];

  typedef __hip_bfloat16 bf;
  const size_t MB = 1u << 20;
  const size_t KB = 1u << 10;
  char* ws = (char*)d_ws;
  // -------- attention layout (peak 120 MiB) --------
  bf* PR = (bf*)(ws);                      // [8192][4096]  0..64M   P, then R in place
  bf* wot = (bf*)(ws + 64 * MB);           // [512][4096]   64..68M  (pre-loop only)
  bf* wqbf = (bf*)(ws + 68 * MB);          // [8][512][512] 68..72M  (pre-P)
  bf* wkbf = (bf*)(ws + 72 * MB);          // 72..76M
  bf* wvbf = (bf*)(ws + 76 * MB);          // 76..80M (pre-loop)
  bf* wqkt = (bf*)(ws + 80 * MB);          // 80..84M (P only)
  bf* sc = (bf*)(ws + 64 * MB);            // [16][1024][1024] 64..96M (loop)
  bf* kbf = (bf*)(ws + 96 * MB);           // [8192][512]   96..104M
  bf* vbft = (bf*)(ws + 104 * MB);         // [8][512][1024] 104..112M
  bf* qbf = (bf*)(ws + 112 * MB);          // [8192][512]   112..120M (dead after P)
  bf* wvot = (bf*)(ws + 112 * MB);         // [512][4096]   112..116M (after P)
  float* u = (float*)(ws + 116 * MB);                 // [8][8192] 256K
  float* w = (float*)(ws + 116 * MB + 256 * KB);      // 256K
  float* rsum = (float*)(ws + 116 * MB + 512 * KB);   // [64][1024] 256K
  float* t1 = (float*)(ws + 116 * MB + 768 * KB);     // [8][512]
  float* t2 = (float*)(ws + 116 * MB + 784 * KB);
  float* cv = (float*)(ws + 116 * MB + 800 * KB);     // [8]
  float* bvo = (float*)(ws + 116 * MB + 804 * KB);    // [512]
  // -------- post-attention (dead-region reuse, stream-order audited) --------
  float* mhap = (float*)(ws + 64 * MB);    // 2x[8192][512] f32 partials 64..96M (over sc)
  float* xbuf = (float*)(ws);              // [8192][512] f32  0..16M (over R, dead after mha)
  bf* xb = (bf*)(ws + 16 * MB);            // [8192][512] bf16 16..24M
  bf* h0 = (bf*)(ws + 24 * MB);            // [8192][2048] 24..56M
  bf* h1 = (bf*)(ws + 56 * MB);            // [8192][2048] 56..88M (over mhap, dead after LN0)
  float* ffp = (float*)(ws + 24 * MB);     // 2x[8192][512] f32 partials 24..56M (over h0, dead after FF2)
  bf* w0t = (bf*)(ws + 96 * MB);           // [2048][512]  96..98M  (over kbf, dead)
  bf* w1t = (bf*)(ws + 98 * MB);           // [2048][2048] 98..106M
  bf* w2t = (bf*)(ws + 106 * MB);          // [512][2048]  106..108M

  const size_t SD = (size_t)Sd * Dd;       // 524288
  const size_t DD = (size_t)Dd * Dd;       // 262144
  const size_t SS = (size_t)Sd * Sd;       // 1048576
  const size_t SDH = (size_t)Sd * Hd * Dd; // 4194304
  const float* np = nullptr;

  // ---- conversions ----
  conv3<<<dim3(2048, 2), 256, 0, stream>>>(Q, K, K, qbf, kbf, kbf);
  conv3<<<dim3(1024, 3), 256, 0, stream>>>(WQ, WK, WV, wqbf, wkbf, wvbf);
  tconv<<<dim3(8, 16, 8), 256, 0, stream>>>(V, vbft, Dd, Sd, SD, SD);
  tconv<<<dim3(8, 64, 1), 256, 0, stream>>>(Wo, wot, Dd, Hd * Dd, 0, 0);

  // ---- wqkt fold + P (while qbf alive) ----
  bt_gemm<EPI_BF16><<<dim3(4, 4, 8), 256, 0, stream>>>(
      wkbf, Dd, 0, DD, wqbf, Dd, 0, DD, np, 0, 0,
      wqkt, Dd, 0, DD, Dd, 1.f, 3, np, np, np, np, np);
  big_gemm<EPI_BF16><<<dim3(16, 32, 1), 512, 0, stream>>>(
      qbf, Dd, 0, 0, wqkt, 0, np, PR, Hd * Dd, 0, Dd, 1.f, np, np, np, np, np);

  // ---- remaining precompute (qbf region now dead) ----
  bt_gemm<EPI_BF16><<<dim3(4, 4, 8), 256, 0, stream>>>(
      wot, Hd * Dd, 0, 512, wvbf, Dd, 0, DD, np, 0, 0,
      wvot, Hd * Dd, 0, 512, Dd, 1.f, 3, np, np, np, np, np);
  tvec<<<dim3(1024, 2), 256, 0, stream>>>(WQ, bK, WK, bQ, t1, t2);
  uw_kernel<<<Bd * Sd, 256, 0, stream>>>(Q, K, t1, t2, u, w);
  cvec<<<8, 256, 0, stream>>>(bQ, bK, cv);
  bvo_kernel<<<128, 256, 0, stream>>>(wot, bV, bo, bvo);
  hipMemsetAsync(rsum, 0, 64 * 1024 * sizeof(float), stream);

  // ---- attention middle: 2 batches/iter; z-slice->XCD affinity ----
  for (int bp = 0; bp < 4; ++bp) {
    const bf* Ap = PR + (size_t)bp * 2 * SDH;
    big_gemm<EPI_SCORES><<<dim3(4, 4, 16), 512, 0, stream>>>(
        Ap, Hd * Dd, SDH, 512, kbf + (size_t)bp * 2 * SD, SD, np,
        sc, Sd, SS, Dd, 1.f / (float)Dd,
        u + bp * 2048, w + bp * 2048, cv, rsum + bp * 16384, np);
    bt_gemm<EPI_PV, 1><<<dim3(4, 8, 16), 256, 0, stream>>>(
        sc, Sd, 8 * SS, SS, vbft + (size_t)bp * 2 * SD, Sd, SD, 0, np, 0, 0,
        (void*)Ap, Hd * Dd, SDH, 512, Sd, 1.f, 3,
        np, np, np, rsum + bp * 16384, np);
  }

  // ---- mha partials: split-K (z=half), p_z = Rcat[:,zK/2:] @ Wvo[:,zK/2:]^T ----
  bt_gemm<EPI_F32><<<dim3(4, 64, 2), 256, 0, stream>>>(
      PR, Hd * Dd, 2048, 0, wvot, Hd * Dd, 2048, 0, np, 0, 0,
      mhap, Dd, SDH, 0, 2048, 1.f, 0, np, np, np, np, np);
  // x = LN(Q + p0 + p1 + bvo)
  add_ln3<<<Bd * Sd, 256, 0, stream>>>(Q, mhap, mhap + SDH, bvo, ln0g, ln0b, xbuf, xb);

  // ---- FF ----
  tconv<<<dim3(32, 8, 1), 256, 0, stream>>>(W0, w0t, Fd, Dd, 0, 0);
  tconv<<<dim3(32, 32, 1), 256, 0, stream>>>(W1, w1t, Fd, Fd, 0, 0);
  tconv<<<dim3(8, 32, 1), 256, 0, stream>>>(W2, w2t, Dd, Fd, 0, 0);

  big_gemm<EPI_BNPRELU><<<dim3(8, 32, 1), 512, 0, stream>>>(
      xb, Dd, 0, 0, w0t, 0, b0, h0, Fd, 0, Dd, 1.f, g0, be0, m0, v0, a0);
  big_gemm<EPI_BNPRELU><<<dim3(8, 32, 1), 512, 0, stream>>>(
      h0, Fd, 0, 0, w1t, 0, b1, h1, Fd, 0, Fd, 1.f, g1, be1, m1, v1, a1);
  // ff partials: split-K (z=half) of h1 @ w2t^T
  bt_gemm<EPI_F32><<<dim3(4, 64, 2), 256, 0, stream>>>(
      h1, Fd, 1024, 0, w2t, Fd, 1024, 0, np, 0, 0,
      ffp, Dd, SDH, 0, 1024, 1.f, 0, np, np, np, np, np);
  // out = LN(x + f0 + f1 + b2)
  add_ln3<<<Bd * Sd, 256, 0, stream>>>(xbuf, ffp, ffp + SDH, b2, ln1g, ln1b, (float*)d_out, nullptr);
}